// Round 1
// baseline (649.183 us; speedup 1.0000x reference)
//
#include <hip/hip_runtime.h>
#include <math.h>

#define Hh 96
#define Ww 96
#define HW 9216
#define CIN 64
#define CMID 128
#define NAT_SCALE 11.313708498984761f   // sqrt(128)

// ---------------- GroupNorm: one block per (batch, group) ----------------
__global__ __launch_bounds__(256) void gn_kernel(const float* __restrict__ x,
    const float* __restrict__ gw, const float* __restrict__ gb,
    float* __restrict__ xn)
{
    int blk = blockIdx.x;            // b*16 + g
    int b = blk >> 4, g = blk & 15;
    int tid = threadIdx.x;
    const int N = 4 * HW;            // 4 channels per group
    size_t base = ((size_t)(b * CIN + g * 4)) * HW;

    float s = 0.f, s2 = 0.f;
    for (int idx = tid; idx < N; idx += 256) {
        float v = x[base + idx];
        s += v; s2 += v * v;
    }
    __shared__ float rs[256], rs2[256];
    rs[tid] = s; rs2[tid] = s2;
    __syncthreads();
    for (int off = 128; off > 0; off >>= 1) {
        if (tid < off) { rs[tid] += rs[tid + off]; rs2[tid] += rs2[tid + off]; }
        __syncthreads();
    }
    float mean = rs[0] / (float)N;
    float var  = rs2[0] / (float)N - mean * mean;
    float rstd = rsqrtf(var + 1e-5f);
    for (int idx = tid; idx < N; idx += 256) {
        int c = g * 4 + idx / HW;
        float v = x[base + idx];
        xn[base + idx] = (v - mean) * rstd * gw[c] + gb[c];
    }
}

// ------- 3x3 conv (64->128, pad 1) + bias + exact GELU, 8x8 LDS tile -------
__global__ __launch_bounds__(256) void conv_kernel(const float* __restrict__ xn,
    const float* __restrict__ cw, const float* __restrict__ cb,
    float* __restrict__ f)
{
    __shared__ float tile[CIN * 100];        // [c][10*10], 25.6 KB
    int blk = blockIdx.x;                    // b*144 + tile
    int b = blk / 144, t = blk % 144;
    int ty = t / 12, tx = t % 12;
    int y0 = ty * 8, x0 = tx * 8;
    int tid = threadIdx.x;

    for (int idx = tid; idx < CIN * 100; idx += 256) {
        int c = idx / 100, r = idx % 100;
        int ly = r / 10, lx = r % 10;
        int gy = y0 + ly - 1, gx = x0 + lx - 1;
        float v = 0.f;
        if (gy >= 0 && gy < Hh && gx >= 0 && gx < Ww)
            v = xn[((size_t)(b * CIN + c)) * HW + gy * Ww + gx];
        tile[idx] = v;
    }
    __syncthreads();

    int wid = tid >> 6, lane = tid & 63;
    int y = lane >> 3, xq = lane & 7;
    int obase = wid * 32;                    // 4 waves x 32 output channels

    float acc[32];
    #pragma unroll
    for (int oi = 0; oi < 32; ++oi) acc[oi] = cb[obase + oi];

    #pragma unroll 2
    for (int c = 0; c < CIN; ++c) {
        int pbase = c * 100 + y * 10 + xq;
        float p[9];
        #pragma unroll
        for (int kh = 0; kh < 3; ++kh)
            #pragma unroll
            for (int kw = 0; kw < 3; ++kw)
                p[kh * 3 + kw] = tile[pbase + kh * 10 + kw];
        int wb = __builtin_amdgcn_readfirstlane(obase * 576 + c * 9);
        #pragma unroll
        for (int oi = 0; oi < 32; ++oi) {
            #pragma unroll
            for (int k9 = 0; k9 < 9; ++k9)
                acc[oi] = fmaf(p[k9], cw[wb + oi * 576 + k9], acc[oi]);
        }
    }

    int pout = (y0 + y) * Ww + x0 + xq;
    #pragma unroll
    for (int oi = 0; oi < 32; ++oi) {
        float v = acc[oi];
        float gg = 0.5f * v * (1.f + erff(v * 0.70710678118654752f));
        f[((size_t)(b * CMID + obase + oi)) * HW + pout] = gg;
    }
}

// ----- 1x1 QKV: 3 waves/block (one per matrix), 64 positions per block -----
// writes NHWC ([p][c]) via LDS transpose for coalesced stores
__global__ __launch_bounds__(192) void qkv_kernel(const float* __restrict__ f,
    const float* __restrict__ qw, const float* __restrict__ qb,
    const float* __restrict__ kw_, const float* __restrict__ kb,
    const float* __restrict__ vw, const float* __restrict__ vb,
    float* __restrict__ qo, float* __restrict__ ko, float* __restrict__ vo)
{
    __shared__ float tr[3][32 * 65];         // per-wave transpose buffer
    int tid = threadIdx.x;
    int m = tid >> 6, lane = tid & 63;
    int gp = blockIdx.x * 64 + lane;         // global position (b*9216+p)
    int b = gp / HW, pl = gp % HW;

    const float* Wm = (m == 0) ? qw : (m == 1) ? kw_ : vw;
    const float* Bm = (m == 0) ? qb : (m == 1) ? kb : vb;
    float*       Om = (m == 0) ? qo : (m == 1) ? ko : vo;

    for (int oc = 0; oc < CMID; oc += 32) {
        float acc[32];
        #pragma unroll
        for (int oi = 0; oi < 32; ++oi) acc[oi] = Bm[oc + oi];

        #pragma unroll 2
        for (int c0 = 0; c0 < CMID; c0 += 8) {
            float fr[8];
            #pragma unroll
            for (int cc = 0; cc < 8; ++cc)
                fr[cc] = f[((size_t)(b * CMID + c0 + cc)) * HW + pl];
            int wb = __builtin_amdgcn_readfirstlane(oc * CMID + c0);
            #pragma unroll
            for (int oi = 0; oi < 32; ++oi)
                #pragma unroll
                for (int cc = 0; cc < 8; ++cc)
                    acc[oi] = fmaf(fr[cc], Wm[wb + oi * CMID + cc], acc[oi]);
        }

        // wave-private LDS transpose, then coalesced NHWC stores
        #pragma unroll
        for (int oi = 0; oi < 32; ++oi) tr[m][oi * 65 + lane] = acc[oi];
        int oi = lane & 31, ph = lane >> 5;
        #pragma unroll
        for (int pp = 0; pp < 32; ++pp) {
            int p_loc = ph * 32 + pp;
            Om[((size_t)(blockIdx.x * 64 + p_loc)) * CMID + oc + oi] =
                tr[m][oi * 65 + p_loc];
        }
    }
}

// -------- 7x7 neighborhood attention, one wave per query pixel --------
__global__ __launch_bounds__(256) void nat_kernel(const float* __restrict__ q,
    const float* __restrict__ k, const float* __restrict__ v,
    float* __restrict__ out)
{
    int tid = threadIdx.x;
    int wid = tid >> 6, lane = tid & 63;
    int qidx = blockIdx.x * 4 + wid;         // < 18432
    int b = qidx / HW, r = qidx % HW;
    int i = r / Ww, j = r % Ww;
    int si = i - 3; si = si < 0 ? 0 : (si > Hh - 7 ? Hh - 7 : si);
    int sj = j - 3; sj = sj < 0 ? 0 : (sj > Ww - 7 ? Ww - 7 : sj);

    const float* qp = q + (size_t)qidx * CMID;
    float q0 = qp[lane], q1 = qp[lane + 64];
    int pbase = b * HW + si * Ww + sj;

    float logit = -INFINITY;
    #pragma unroll
    for (int t = 0; t < 49; ++t) {
        int a = t / 7, kk = t % 7;
        const float* kp = k + (size_t)(pbase + a * Ww + kk) * CMID;
        float part = q0 * kp[lane] + q1 * kp[lane + 64];
        #pragma unroll
        for (int d = 1; d < 64; d <<= 1) part += __shfl_xor(part, d);
        if (lane == t) logit = part;
    }
    logit *= NAT_SCALE;

    float mx = logit;
    #pragma unroll
    for (int d = 1; d < 64; d <<= 1) mx = fmaxf(mx, __shfl_xor(mx, d));
    float e = (lane < 49) ? expf(logit - mx) : 0.f;
    float s = e;
    #pragma unroll
    for (int d = 1; d < 64; d <<= 1) s += __shfl_xor(s, d);
    float wa = e / s;

    float o0 = 0.f, o1 = 0.f;
    #pragma unroll
    for (int t = 0; t < 49; ++t) {
        int a = t / 7, kk = t % 7;
        const float* vp = v + (size_t)(pbase + a * Ww + kk) * CMID;
        float aw = __shfl(wa, t);
        o0 = fmaf(aw, vp[lane], o0);
        o1 = fmaf(aw, vp[lane + 64], o1);
    }
    out[((size_t)(b * CMID) + lane) * HW + i * Ww + j] = o0;
    out[((size_t)(b * CMID) + lane + 64) * HW + i * Ww + j] = o1;
}

extern "C" void kernel_launch(void* const* d_in, const int* in_sizes, int n_in,
                              void* d_out, int out_size, void* d_ws, size_t ws_size,
                              hipStream_t stream) {
    const float* x      = (const float*)d_in[0];
    const float* gn_w   = (const float*)d_in[1];
    const float* gn_b   = (const float*)d_in[2];
    const float* conv_w = (const float*)d_in[3];
    const float* conv_b = (const float*)d_in[4];
    const float* q_w    = (const float*)d_in[5];
    const float* q_b    = (const float*)d_in[6];
    const float* k_w    = (const float*)d_in[7];
    const float* k_b    = (const float*)d_in[8];
    const float* v_w    = (const float*)d_in[9];
    const float* v_b    = (const float*)d_in[10];

    float* ws = (float*)d_ws;
    float* xn = ws;                          // 1,179,648
    float* f  = xn + (size_t)2 * CIN * HW;   // 2,359,296
    float* qb_ = f + (size_t)2 * CMID * HW;
    float* kb_ = qb_ + (size_t)2 * CMID * HW;
    float* vb_ = kb_ + (size_t)2 * CMID * HW;

    gn_kernel<<<32, 256, 0, stream>>>(x, gn_w, gn_b, xn);
    conv_kernel<<<288, 256, 0, stream>>>(xn, conv_w, conv_b, f);
    qkv_kernel<<<288, 192, 0, stream>>>(f, q_w, q_b, k_w, k_b, v_w, v_b,
                                        qb_, kb_, vb_);
    nat_kernel<<<4608, 256, 0, stream>>>(qb_, kb_, vb_, (float*)d_out);
}

// Round 2
// 345.262 us; speedup vs baseline: 1.8803x; 1.8803x over previous
//
#include <hip/hip_runtime.h>
#include <math.h>

#define Hh 96
#define Ww 96
#define HW 9216
#define CIN 64
#define CMID 128
#define NAT_SCALE 11.313708498984761f   // sqrt(128), multiplies logits

// ---------- GN stats: one block per (batch, group), mean+rstd only ----------
__global__ __launch_bounds__(1024) void gn_stats_kernel(const float* __restrict__ x,
    float* __restrict__ stats)
{
    int blk = blockIdx.x;                  // b*16+g ; channels g*4..g*4+3
    int tid = threadIdx.x;
    size_t base = (size_t)blk * (4 * HW);  // == (b*CIN + g*4)*HW since CIN=64
    float s = 0.f, s2 = 0.f;
    for (int idx = tid; idx < 4 * HW; idx += 1024) {
        float v = x[base + idx];
        s += v; s2 += v * v;
    }
    #pragma unroll
    for (int d = 1; d < 64; d <<= 1) {
        s  += __shfl_xor(s, d);
        s2 += __shfl_xor(s2, d);
    }
    __shared__ float as[16], as2[16];
    int wid = tid >> 6, lane = tid & 63;
    if (lane == 0) { as[wid] = s; as2[wid] = s2; }
    __syncthreads();
    if (tid == 0) {
        float S = 0.f, S2 = 0.f;
        #pragma unroll
        for (int w = 0; w < 16; ++w) { S += as[w]; S2 += as2[w]; }
        const float invN = 1.f / (float)(4 * HW);
        float mean = S * invN;
        float var  = S2 * invN - mean * mean;
        stats[blk * 2]     = mean;
        stats[blk * 2 + 1] = rsqrtf(var + 1e-5f);
    }
}

// --- 3x3 conv (64->128) + GN-on-the-fly + bias + exact GELU ---
// grid = 2b * 144 tiles * 4 oc-groups = 1152 blocks; wave owns 8 oc
__global__ __launch_bounds__(256) void conv_kernel(const float* __restrict__ x,
    const float* __restrict__ stats,
    const float* __restrict__ gw, const float* __restrict__ gb,
    const float* __restrict__ cw, const float* __restrict__ cb,
    float* __restrict__ f)
{
    __shared__ float tile[CIN * 120];        // rows padded 10->12: 2-way banks (free)
    int bid = blockIdx.x;
    int swz = (bid & 7) * 144 + (bid >> 3);  // XCD-chunked, bijective (1152 = 8*144)
    int ocg = swz & 3;
    int bt  = swz >> 2;                      // b*144 + t
    int b = bt / 144, t = bt % 144;
    int ty = t / 12, tx = t % 12;
    int y0 = ty * 8, x0 = tx * 8;
    int tid = threadIdx.x;

    for (int idx = tid; idx < CIN * 100; idx += 256) {
        int c = idx / 100, r = idx - c * 100;
        int ly = r / 10, lx = r - ly * 10;
        int gy = y0 + ly - 1, gx = x0 + lx - 1;
        float val = 0.f;
        if (gy >= 0 && gy < Hh && gx >= 0 && gx < Ww) {
            float xv = x[((size_t)(b * CIN + c)) * HW + gy * Ww + gx];
            int sg = (b * 16 + (c >> 2)) * 2;
            val = (xv - stats[sg]) * stats[sg + 1] * gw[c] + gb[c];
        }
        tile[c * 120 + ly * 12 + lx] = val;
    }
    __syncthreads();

    int wid = tid >> 6, lane = tid & 63;
    int y = lane >> 3, xq = lane & 7;
    int ob = ocg * 32 + wid * 8;             // this wave's 8 output channels

    float acc[8];
    #pragma unroll
    for (int oi = 0; oi < 8; ++oi) acc[oi] = cb[ob + oi];

    #pragma unroll 4
    for (int c = 0; c < CIN; ++c) {
        int pbase = c * 120 + y * 12 + xq;
        float p[9];
        #pragma unroll
        for (int kh = 0; kh < 3; ++kh)
            #pragma unroll
            for (int kw = 0; kw < 3; ++kw)
                p[kh * 3 + kw] = tile[pbase + kh * 12 + kw];
        int wb = __builtin_amdgcn_readfirstlane(ob * 576 + c * 9);
        #pragma unroll
        for (int oi = 0; oi < 8; ++oi)
            #pragma unroll
            for (int k9 = 0; k9 < 9; ++k9)
                acc[oi] = fmaf(p[k9], cw[wb + oi * 576 + k9], acc[oi]);
    }

    int pout = (y0 + y) * Ww + x0 + xq;
    #pragma unroll
    for (int oi = 0; oi < 8; ++oi) {
        float v = acc[oi];
        f[((size_t)(b * CMID + ob + oi)) * HW + pout] =
            0.5f * v * (1.f + erff(v * 0.70710678118654752f));
    }
}

// ----- 1x1 QKV: block = (pos-block of 64, matrix); 4 waves x 32 oc each -----
__global__ __launch_bounds__(256) void qkv_kernel(const float* __restrict__ f,
    const float* __restrict__ qw, const float* __restrict__ qb,
    const float* __restrict__ kw_, const float* __restrict__ kb,
    const float* __restrict__ vw, const float* __restrict__ vb,
    float* __restrict__ qo, float* __restrict__ ko, float* __restrict__ vo)
{
    __shared__ float tr[4][32 * 65];
    int bid = blockIdx.x;
    int swz = (bid & 7) * 108 + (bid >> 3);  // 864 = 8*108, bijective
    int m = swz / 288, pblk = swz - (swz / 288) * 288;
    int tid = threadIdx.x, wid = tid >> 6, lane = tid & 63;
    int gp = pblk * 64 + lane;
    int b = gp / HW, pl = gp - b * HW;

    const float* Wm = (m == 0) ? qw : (m == 1) ? kw_ : vw;
    const float* Bm = (m == 0) ? qb : (m == 1) ? kb : vb;
    float*       Om = (m == 0) ? qo : (m == 1) ? ko : vo;

    int oc = wid * 32;
    float acc[32];
    #pragma unroll
    for (int oi = 0; oi < 32; ++oi) acc[oi] = Bm[oc + oi];

    #pragma unroll 2
    for (int c0 = 0; c0 < CMID; c0 += 8) {
        float fr[8];
        #pragma unroll
        for (int cc = 0; cc < 8; ++cc)
            fr[cc] = f[((size_t)(b * CMID + c0 + cc)) * HW + pl];
        int wb = __builtin_amdgcn_readfirstlane(oc * CMID + c0);
        #pragma unroll
        for (int oi = 0; oi < 32; ++oi)
            #pragma unroll
            for (int cc = 0; cc < 8; ++cc)
                acc[oi] = fmaf(fr[cc], Wm[wb + oi * CMID + cc], acc[oi]);
    }

    #pragma unroll
    for (int oi = 0; oi < 32; ++oi) tr[wid][oi * 65 + lane] = acc[oi];
    __syncthreads();
    int oi = lane & 31, ph = lane >> 5;
    #pragma unroll
    for (int pp = 0; pp < 32; ++pp) {
        int p_loc = ph * 32 + pp;
        Om[((size_t)(pblk * 64 + p_loc)) * CMID + oc + oi] = tr[wid][oi * 65 + p_loc];
    }
}

// -------- 7x7 NAT, one wave per query, float2 channel pairs --------
__global__ __launch_bounds__(256) void nat_kernel(const float* __restrict__ q,
    const float* __restrict__ k, const float* __restrict__ v,
    float* __restrict__ out)
{
    int bid = blockIdx.x;
    int swz = (bid & 7) * 576 + (bid >> 3);  // 4608 = 8*576: chunk queries per XCD
    int tid = threadIdx.x;
    int wid = tid >> 6, lane = tid & 63;
    int qidx = swz * 4 + wid;
    int b = qidx / HW, r = qidx - b * HW;
    int i = r / Ww, j = r - i * Ww;
    int si = i - 3; si = si < 0 ? 0 : (si > Hh - 7 ? Hh - 7 : si);
    int sj = j - 3; sj = sj < 0 ? 0 : (sj > Ww - 7 ? Ww - 7 : sj);

    const float2* qp = (const float2*)(q + (size_t)qidx * CMID);
    float2 qv = qp[lane];                    // channels 2*lane, 2*lane+1
    int pbase = b * HW + si * Ww + sj;

    float logit = 0.f;
    #pragma unroll
    for (int t = 0; t < 49; ++t) {
        int a = t / 7, kk = t - a * 7;
        const float2* kp = (const float2*)(k + (size_t)(pbase + a * Ww + kk) * CMID);
        float2 kv = kp[lane];
        float part = qv.x * kv.x + qv.y * kv.y;
        #pragma unroll
        for (int d = 1; d < 64; d <<= 1) part += __shfl_xor(part, d);
        if (lane == t) logit = part;
    }
    logit *= NAT_SCALE;
    float ml = (lane < 49) ? logit : -INFINITY;
    float mx = ml;
    #pragma unroll
    for (int d = 1; d < 64; d <<= 1) mx = fmaxf(mx, __shfl_xor(mx, d));
    float e = (lane < 49) ? expf(logit - mx) : 0.f;
    float s = e;
    #pragma unroll
    for (int d = 1; d < 64; d <<= 1) s += __shfl_xor(s, d);
    float wa = e / s;

    float2 o = {0.f, 0.f};
    #pragma unroll
    for (int t = 0; t < 49; ++t) {
        int a = t / 7, kk = t - a * 7;
        const float2* vp = (const float2*)(v + (size_t)(pbase + a * Ww + kk) * CMID);
        float aw = __shfl(wa, t);
        float2 vv = vp[lane];
        o.x = fmaf(aw, vv.x, o.x);
        o.y = fmaf(aw, vv.y, o.y);
    }
    size_t ob = ((size_t)(b * CMID + 2 * lane)) * HW + i * Ww + j;
    out[ob]      = o.x;
    out[ob + HW] = o.y;
}

extern "C" void kernel_launch(void* const* d_in, const int* in_sizes, int n_in,
                              void* d_out, int out_size, void* d_ws, size_t ws_size,
                              hipStream_t stream) {
    const float* x      = (const float*)d_in[0];
    const float* gn_w   = (const float*)d_in[1];
    const float* gn_b   = (const float*)d_in[2];
    const float* conv_w = (const float*)d_in[3];
    const float* conv_b = (const float*)d_in[4];
    const float* q_w    = (const float*)d_in[5];
    const float* q_b    = (const float*)d_in[6];
    const float* k_w    = (const float*)d_in[7];
    const float* k_b    = (const float*)d_in[8];
    const float* v_w    = (const float*)d_in[9];
    const float* v_b    = (const float*)d_in[10];

    float* ws    = (float*)d_ws;
    float* stats = ws;                        // 64 floats
    float* f     = ws + 64;                   // 2,359,296
    float* qb_   = f   + (size_t)2 * CMID * HW;
    float* kb_   = qb_ + (size_t)2 * CMID * HW;
    float* vb_   = kb_ + (size_t)2 * CMID * HW;

    gn_stats_kernel<<<32, 1024, 0, stream>>>(x, stats);
    conv_kernel<<<1152, 256, 0, stream>>>(x, stats, gn_w, gn_b, conv_w, conv_b, f);
    qkv_kernel<<<864, 256, 0, stream>>>(f, q_w, q_b, k_w, k_b, v_w, v_b,
                                        qb_, kb_, vb_);
    nat_kernel<<<4608, 256, 0, stream>>>(qb_, kb_, vb_, (float*)d_out);
}

// Round 3
// 305.088 us; speedup vs baseline: 2.1279x; 1.1317x over previous
//
#include <hip/hip_runtime.h>
#include <math.h>

#define Hh 96
#define Ww 96
#define HW 9216
#define CIN 64
#define CMID 128
#define NAT_SCALE 11.313708498984761f   // sqrt(128), multiplies logits

// ---------- GN stats: one block per (batch, group), mean+rstd only ----------
__global__ __launch_bounds__(1024) void gn_stats_kernel(const float* __restrict__ x,
    float* __restrict__ stats)
{
    int blk = blockIdx.x;                  // b*16+g ; channels g*4..g*4+3
    int tid = threadIdx.x;
    size_t base = (size_t)blk * (4 * HW);  // == (b*CIN + g*4)*HW since CIN=64
    float s = 0.f, s2 = 0.f;
    for (int idx = tid; idx < 4 * HW; idx += 1024) {
        float v = x[base + idx];
        s += v; s2 += v * v;
    }
    #pragma unroll
    for (int d = 1; d < 64; d <<= 1) {
        s  += __shfl_xor(s, d);
        s2 += __shfl_xor(s2, d);
    }
    __shared__ float as[16], as2[16];
    int wid = tid >> 6, lane = tid & 63;
    if (lane == 0) { as[wid] = s; as2[wid] = s2; }
    __syncthreads();
    if (tid == 0) {
        float S = 0.f, S2 = 0.f;
        #pragma unroll
        for (int w = 0; w < 16; ++w) { S += as[w]; S2 += as2[w]; }
        const float invN = 1.f / (float)(4 * HW);
        float mean = S * invN;
        float var  = S2 * invN - mean * mean;
        stats[blk * 2]     = mean;
        stats[blk * 2 + 1] = rsqrtf(var + 1e-5f);
    }
}

// --- 3x3 conv (64->128) + GN-on-the-fly + bias + exact GELU ---
// grid = 2b * 144 tiles * 4 oc-groups = 1152 blocks; wave owns 8 oc
__global__ __launch_bounds__(256) void conv_kernel(const float* __restrict__ x,
    const float* __restrict__ stats,
    const float* __restrict__ gw, const float* __restrict__ gb,
    const float* __restrict__ cw, const float* __restrict__ cb,
    float* __restrict__ f)
{
    __shared__ float tile[CIN * 120];        // rows padded 10->12: 2-way banks (free)
    int bid = blockIdx.x;
    int swz = (bid & 7) * 144 + (bid >> 3);  // XCD-chunked, bijective (1152 = 8*144)
    int ocg = swz & 3;
    int bt  = swz >> 2;                      // b*144 + t
    int b = bt / 144, t = bt % 144;
    int ty = t / 12, tx = t % 12;
    int y0 = ty * 8, x0 = tx * 8;
    int tid = threadIdx.x;

    for (int idx = tid; idx < CIN * 100; idx += 256) {
        int c = idx / 100, r = idx - c * 100;
        int ly = r / 10, lx = r - ly * 10;
        int gy = y0 + ly - 1, gx = x0 + lx - 1;
        float val = 0.f;
        if (gy >= 0 && gy < Hh && gx >= 0 && gx < Ww) {
            float xv = x[((size_t)(b * CIN + c)) * HW + gy * Ww + gx];
            int sg = (b * 16 + (c >> 2)) * 2;
            val = (xv - stats[sg]) * stats[sg + 1] * gw[c] + gb[c];
        }
        tile[c * 120 + ly * 12 + lx] = val;
    }
    __syncthreads();

    int wid = tid >> 6, lane = tid & 63;
    int y = lane >> 3, xq = lane & 7;
    int ob = ocg * 32 + wid * 8;             // this wave's 8 output channels

    float acc[8];
    #pragma unroll
    for (int oi = 0; oi < 8; ++oi) acc[oi] = cb[ob + oi];

    #pragma unroll 4
    for (int c = 0; c < CIN; ++c) {
        int pbase = c * 120 + y * 12 + xq;
        float p[9];
        #pragma unroll
        for (int kh = 0; kh < 3; ++kh)
            #pragma unroll
            for (int kw = 0; kw < 3; ++kw)
                p[kh * 3 + kw] = tile[pbase + kh * 12 + kw];
        int wb = __builtin_amdgcn_readfirstlane(ob * 576 + c * 9);
        #pragma unroll
        for (int oi = 0; oi < 8; ++oi)
            #pragma unroll
            for (int k9 = 0; k9 < 9; ++k9)
                acc[oi] = fmaf(p[k9], cw[wb + oi * 576 + k9], acc[oi]);
    }

    int pout = (y0 + y) * Ww + x0 + xq;
    #pragma unroll
    for (int oi = 0; oi < 8; ++oi) {
        float v = acc[oi];
        f[((size_t)(b * CMID + ob + oi)) * HW + pout] =
            0.5f * v * (1.f + erff(v * 0.70710678118654752f));
    }
}

// ----- 1x1 QKV: block = (pos-block of 64, matrix); 4 waves x 32 oc each -----
__global__ __launch_bounds__(256) void qkv_kernel(const float* __restrict__ f,
    const float* __restrict__ qw, const float* __restrict__ qb,
    const float* __restrict__ kw_, const float* __restrict__ kb,
    const float* __restrict__ vw, const float* __restrict__ vb,
    float* __restrict__ qo, float* __restrict__ ko, float* __restrict__ vo)
{
    __shared__ float tr[4][32 * 65];
    int bid = blockIdx.x;
    int swz = (bid & 7) * 108 + (bid >> 3);  // 864 = 8*108, bijective
    int m = swz / 288, pblk = swz - (swz / 288) * 288;
    int tid = threadIdx.x, wid = tid >> 6, lane = tid & 63;
    int gp = pblk * 64 + lane;
    int b = gp / HW, pl = gp - b * HW;

    const float* Wm = (m == 0) ? qw : (m == 1) ? kw_ : vw;
    const float* Bm = (m == 0) ? qb : (m == 1) ? kb : vb;
    float*       Om = (m == 0) ? qo : (m == 1) ? ko : vo;

    int oc = wid * 32;
    float acc[32];
    #pragma unroll
    for (int oi = 0; oi < 32; ++oi) acc[oi] = Bm[oc + oi];

    #pragma unroll 2
    for (int c0 = 0; c0 < CMID; c0 += 8) {
        float fr[8];
        #pragma unroll
        for (int cc = 0; cc < 8; ++cc)
            fr[cc] = f[((size_t)(b * CMID + c0 + cc)) * HW + pl];
        int wb = __builtin_amdgcn_readfirstlane(oc * CMID + c0);
        #pragma unroll
        for (int oi = 0; oi < 32; ++oi)
            #pragma unroll
            for (int cc = 0; cc < 8; ++cc)
                acc[oi] = fmaf(fr[cc], Wm[wb + oi * CMID + cc], acc[oi]);
    }

    #pragma unroll
    for (int oi = 0; oi < 32; ++oi) tr[wid][oi * 65 + lane] = acc[oi];
    __syncthreads();
    int oi = lane & 31, ph = lane >> 5;
    #pragma unroll
    for (int pp = 0; pp < 32; ++pp) {
        int p_loc = ph * 32 + pp;
        Om[((size_t)(pblk * 64 + p_loc)) * CMID + oc + oi] = tr[wid][oi * 65 + p_loc];
    }
}

// -------- 7x7 NAT v2: one wave/query; lane t computes logit t --------
__global__ __launch_bounds__(256) void nat_kernel(const float* __restrict__ q,
    const float* __restrict__ k, const float* __restrict__ v,
    float* __restrict__ out)
{
    int bid = blockIdx.x;
    int swz = (bid & 7) * 576 + (bid >> 3);  // 4608 = 8*576: chunk queries per XCD
    int tid = threadIdx.x;
    int wid = tid >> 6, lane = tid & 63;
    int qidx = __builtin_amdgcn_readfirstlane(swz * 4 + wid);   // wave-uniform
    int b = qidx / HW, r = qidx - b * HW;
    int i = r / Ww, j = r - i * Ww;
    int si = i - 3; si = si < 0 ? 0 : (si > Hh - 7 ? Hh - 7 : si);
    int sj = j - 3; sj = sj < 0 ? 0 : (sj > Ww - 7 ? Ww - 7 : sj);
    int pbase = b * HW + si * Ww + sj;       // uniform

    // ---- phase 1: lane t<49 owns key t, full 128-dim dot in-lane ----
    int t = lane < 49 ? lane : 48;           // clamp idle lanes to a valid row
    int a = t / 7, kk = t - a * 7;
    const float4* kp = (const float4*)(k + (size_t)(pbase + a * Ww + kk) * CMID);
    const float4* qp = (const float4*)(q + (size_t)qidx * CMID);  // uniform -> s_load
    float acc = 0.f;
    #pragma unroll 8
    for (int c = 0; c < 32; ++c) {
        float4 kv = kp[c];
        float4 qv = qp[c];
        acc = fmaf(qv.x, kv.x, acc);
        acc = fmaf(qv.y, kv.y, acc);
        acc = fmaf(qv.z, kv.z, acc);
        acc = fmaf(qv.w, kv.w, acc);
    }
    float logit = (lane < 49) ? acc * NAT_SCALE : -INFINITY;

    // ---- phase 2: softmax across lanes (single pair of butterflies) ----
    float mx = logit;
    #pragma unroll
    for (int d = 1; d < 64; d <<= 1) mx = fmaxf(mx, __shfl_xor(mx, d));
    float e = (lane < 49) ? __expf(logit - mx) : 0.f;
    float s = e;
    #pragma unroll
    for (int d = 1; d < 64; d <<= 1) s += __shfl_xor(s, d);
    float wa = e / s;                        // lane t holds weight t

    // ---- phase 3: PV, lane = channel pair; literal-lane shfl -> readlane ----
    float2 o = {0.f, 0.f};
    #pragma unroll
    for (int tt = 0; tt < 49; ++tt) {
        int aa = tt / 7, kk2 = tt - aa * 7;
        const float2* vp = (const float2*)(v + (size_t)(pbase + aa * Ww + kk2) * CMID);
        float aw = __shfl(wa, tt);           // literal lane -> v_readlane (SGPR)
        float2 vv = vp[lane];
        o.x = fmaf(aw, vv.x, o.x);
        o.y = fmaf(aw, vv.y, o.y);
    }
    size_t ob = ((size_t)(b * CMID + 2 * lane)) * HW + i * Ww + j;
    out[ob]      = o.x;
    out[ob + HW] = o.y;
}

extern "C" void kernel_launch(void* const* d_in, const int* in_sizes, int n_in,
                              void* d_out, int out_size, void* d_ws, size_t ws_size,
                              hipStream_t stream) {
    const float* x      = (const float*)d_in[0];
    const float* gn_w   = (const float*)d_in[1];
    const float* gn_b   = (const float*)d_in[2];
    const float* conv_w = (const float*)d_in[3];
    const float* conv_b = (const float*)d_in[4];
    const float* q_w    = (const float*)d_in[5];
    const float* q_b    = (const float*)d_in[6];
    const float* k_w    = (const float*)d_in[7];
    const float* k_b    = (const float*)d_in[8];
    const float* v_w    = (const float*)d_in[9];
    const float* v_b    = (const float*)d_in[10];

    float* ws    = (float*)d_ws;
    float* stats = ws;                        // 64 floats
    float* f     = ws + 64;                   // 2,359,296
    float* qb_   = f   + (size_t)2 * CMID * HW;
    float* kb_   = qb_ + (size_t)2 * CMID * HW;
    float* vb_   = kb_ + (size_t)2 * CMID * HW;

    gn_stats_kernel<<<32, 1024, 0, stream>>>(x, stats);
    conv_kernel<<<1152, 256, 0, stream>>>(x, stats, gn_w, gn_b, conv_w, conv_b, f);
    qkv_kernel<<<864, 256, 0, stream>>>(f, q_w, q_b, k_w, k_b, v_w, v_b,
                                        qb_, kb_, vb_);
    nat_kernel<<<4608, 256, 0, stream>>>(qb_, kb_, vb_, (float*)d_out);
}

// Round 4
// 257.962 us; speedup vs baseline: 2.5166x; 1.1827x over previous
//
#include <hip/hip_runtime.h>
#include <math.h>

#define Hh 96
#define Ww 96
#define HW 9216
#define CIN 64
#define CMID 128
#define NAT_SCALE 11.313708498984761f   // sqrt(128), multiplies logits

// ---------- GN stats: one block per (batch, group), mean+rstd only ----------
__global__ __launch_bounds__(1024) void gn_stats_kernel(const float* __restrict__ x,
    float* __restrict__ stats)
{
    int blk = blockIdx.x;                  // b*16+g ; channels g*4..g*4+3
    int tid = threadIdx.x;
    size_t base = (size_t)blk * (4 * HW);
    float s = 0.f, s2 = 0.f;
    for (int idx = tid; idx < 4 * HW; idx += 1024) {
        float v = x[base + idx];
        s += v; s2 += v * v;
    }
    #pragma unroll
    for (int d = 1; d < 64; d <<= 1) {
        s  += __shfl_xor(s, d);
        s2 += __shfl_xor(s2, d);
    }
    __shared__ float as[16], as2[16];
    int wid = tid >> 6, lane = tid & 63;
    if (lane == 0) { as[wid] = s; as2[wid] = s2; }
    __syncthreads();
    if (tid == 0) {
        float S = 0.f, S2 = 0.f;
        #pragma unroll
        for (int w = 0; w < 16; ++w) { S += as[w]; S2 += as2[w]; }
        const float invN = 1.f / (float)(4 * HW);
        float mean = S * invN;
        float var  = S2 * invN - mean * mean;
        stats[blk * 2]     = mean;
        stats[blk * 2 + 1] = rsqrtf(var + 1e-5f);
    }
}

// ---------- conv-weight transpose: [oc][c*9+k9] -> [c*9+k9][oc] ----------
__global__ __launch_bounds__(256) void wt_kernel(const float* __restrict__ cw,
    float* __restrict__ cwT)
{
    int t = blockIdx.x * 256 + threadIdx.x;   // 73728 total
    int oc = t & 127, ck = t >> 7;            // ck = c*9+k9
    cwT[t] = cw[oc * 576 + ck];
}

// --- 3x3 conv + GN-on-the-fly + bias + exact GELU; lane = output channel ---
// block: 4 waves = 128 oc x 2 rows x 8 cols; writes f NHWC [b*HW+p][128]
__global__ __launch_bounds__(256) void conv_kernel(const float* __restrict__ x,
    const float* __restrict__ stats,
    const float* __restrict__ gw, const float* __restrict__ gb,
    const float* __restrict__ cwT, const float* __restrict__ cb,
    float* __restrict__ f)
{
    __shared__ float tin[CIN * 48];          // [c][4 rows][12 cols] 12.3KB
    int bid = blockIdx.x;
    int swz = (bid & 7) * 144 + (bid >> 3);  // 1152 = 8*144, bijective
    int b = swz / 576, rem = swz - b * 576;
    int rp = rem / 12, cx = rem - rp * 12;
    int y0 = rp * 2, x0 = cx * 8;
    int tid = threadIdx.x;

    #pragma unroll
    for (int i = 0; i < 10; ++i) {           // stage 64c x 4x10 patch + GN
        int idx = tid + i * 256;
        int c = idx / 40, r2 = idx - c * 40;
        int ry = r2 / 10, rx = r2 - ry * 10;
        int gy = y0 - 1 + ry, gx = x0 - 1 + rx;
        float val = 0.f;
        if (gy >= 0 && gy < Hh && gx >= 0 && gx < Ww) {
            float xv = x[((size_t)(b * CIN + c)) * HW + gy * Ww + gx];
            int sg = (b * 16 + (c >> 2)) * 2;
            val = (xv - stats[sg]) * stats[sg + 1] * gw[c] + gb[c];
        }
        tin[c * 48 + ry * 12 + rx] = val;
    }
    __syncthreads();

    int wid = tid >> 6, lane = tid & 63;
    int oc = (wid & 1) * 64 + lane;          // waves 0,1 / 2,3 split oc halves
    int r = wid >> 1;                        // row 0 or 1 of the tile

    float acc[8];
    float bias = cb[oc];
    #pragma unroll
    for (int p = 0; p < 8; ++p) acc[p] = bias;

    #pragma unroll 2
    for (int c = 0; c < CIN; ++c) {
        float wv[9];                         // per-lane weights, coalesced
        #pragma unroll
        for (int k9 = 0; k9 < 9; ++k9)
            wv[k9] = cwT[(c * 9 + k9) * 128 + oc];
        #pragma unroll
        for (int kh = 0; kh < 3; ++kh) {
            float xr[10];                    // wave-uniform LDS broadcasts
            #pragma unroll
            for (int q4 = 0; q4 < 10; ++q4)
                xr[q4] = tin[c * 48 + (r + kh) * 12 + q4];
            #pragma unroll
            for (int kw = 0; kw < 3; ++kw)
                #pragma unroll
                for (int p = 0; p < 8; ++p)
                    acc[p] = fmaf(wv[kh * 3 + kw], xr[p + kw], acc[p]);
        }
    }

    int prow = (y0 + r) * Ww + x0;
    #pragma unroll
    for (int p = 0; p < 8; ++p) {
        float v = acc[p];
        float g = 0.5f * v * (1.f + erff(v * 0.70710678118654752f));
        f[((size_t)(b * HW + prow + p)) * CMID + oc] = g;   // NHWC, coalesced
    }
}

// ----- 1x1 QKV v2: LDS-staged f; block = (64 pos, matrix); 4 waves x 32 oc -----
__global__ __launch_bounds__(256) void qkv_kernel(const float* __restrict__ f,
    const float* __restrict__ qw, const float* __restrict__ qb,
    const float* __restrict__ kw_, const float* __restrict__ kb,
    const float* __restrict__ vw, const float* __restrict__ vb,
    float* __restrict__ qo, float* __restrict__ ko, float* __restrict__ vo)
{
    __shared__ float fc[CMID * 64];          // f tile transposed to [c][p], 32KB
    __shared__ float tr[4][512];             // rotation-swizzled, 8KB
    int bid = blockIdx.x;
    int swz = (bid & 7) * 108 + (bid >> 3);  // 864 = 8*108, bijective
    int m = swz / 288, pblk = swz - m * 288;
    int tid = threadIdx.x, wid = tid >> 6, lane = tid & 63;
    size_t p0 = (size_t)pblk * 64;

    // stage f[p][c] -> fc[c][p]  (16B/lane reads, L2-resident; clean ds writes)
    const float4* f4 = (const float4*)(f + p0 * CMID);
    #pragma unroll
    for (int it = 0; it < 8; ++it) {
        int cq = it * 4 + wid;
        float4 v4 = f4[(size_t)lane * 32 + cq];
        fc[(cq * 4 + 0) * 64 + lane] = v4.x;
        fc[(cq * 4 + 1) * 64 + lane] = v4.y;
        fc[(cq * 4 + 2) * 64 + lane] = v4.z;
        fc[(cq * 4 + 3) * 64 + lane] = v4.w;
    }
    __syncthreads();

    const float* Wm = (m == 0) ? qw : (m == 1) ? kw_ : vw;
    const float* Bm = (m == 0) ? qb : (m == 1) ? kb : vb;
    float*       Om = (m == 0) ? qo : (m == 1) ? ko : vo;

    int oc = wid * 32;
    float acc[32];
    #pragma unroll
    for (int oi = 0; oi < 32; ++oi) acc[oi] = Bm[oc + oi];

    #pragma unroll 2
    for (int c0 = 0; c0 < CMID; c0 += 8) {
        float fr[8];
        #pragma unroll
        for (int cc = 0; cc < 8; ++cc)
            fr[cc] = fc[(c0 + cc) * 64 + lane];
        int wb = __builtin_amdgcn_readfirstlane(oc * CMID + c0);
        #pragma unroll
        for (int oi = 0; oi < 32; ++oi)
            #pragma unroll
            for (int cc = 0; cc < 8; ++cc)
                acc[oi] = fmaf(fr[cc], Wm[wb + oi * CMID + cc], acc[oi]);
    }

    // wave-private swizzled transpose, 8 oc at a time -> coalesced NHWC stores
    float* trw = &tr[wid][0];
    int oi8 = lane & 7, ph = lane >> 3;
    #pragma unroll
    for (int ocb = 0; ocb < 32; ocb += 8) {
        #pragma unroll
        for (int oi = 0; oi < 8; ++oi)
            trw[oi * 64 + ((lane + oi * 8) & 63)] = acc[ocb + oi];
        #pragma unroll
        for (int pp = 0; pp < 8; ++pp) {
            int p_loc = ph * 8 + pp;
            float v = trw[oi8 * 64 + ((p_loc + oi8 * 8) & 63)];
            Om[(p0 + p_loc) * CMID + oc + ocb + oi8] = v;
        }
    }
}

// -------- 7x7 NAT: one wave/query; lane t computes logit t (unchanged) --------
__global__ __launch_bounds__(256) void nat_kernel(const float* __restrict__ q,
    const float* __restrict__ k, const float* __restrict__ v,
    float* __restrict__ out)
{
    int bid = blockIdx.x;
    int swz = (bid & 7) * 576 + (bid >> 3);  // 4608 = 8*576
    int tid = threadIdx.x;
    int wid = tid >> 6, lane = tid & 63;
    int qidx = __builtin_amdgcn_readfirstlane(swz * 4 + wid);
    int b = qidx / HW, r = qidx - b * HW;
    int i = r / Ww, j = r - i * Ww;
    int si = i - 3; si = si < 0 ? 0 : (si > Hh - 7 ? Hh - 7 : si);
    int sj = j - 3; sj = sj < 0 ? 0 : (sj > Ww - 7 ? Ww - 7 : sj);
    int pbase = b * HW + si * Ww + sj;

    int t = lane < 49 ? lane : 48;
    int a = t / 7, kk = t - a * 7;
    const float4* kp = (const float4*)(k + (size_t)(pbase + a * Ww + kk) * CMID);
    const float4* qp = (const float4*)(q + (size_t)qidx * CMID);
    float acc = 0.f;
    #pragma unroll 8
    for (int c = 0; c < 32; ++c) {
        float4 kv = kp[c];
        float4 qv = qp[c];
        acc = fmaf(qv.x, kv.x, acc);
        acc = fmaf(qv.y, kv.y, acc);
        acc = fmaf(qv.z, kv.z, acc);
        acc = fmaf(qv.w, kv.w, acc);
    }
    float logit = (lane < 49) ? acc * NAT_SCALE : -INFINITY;

    float mx = logit;
    #pragma unroll
    for (int d = 1; d < 64; d <<= 1) mx = fmaxf(mx, __shfl_xor(mx, d));
    float e = (lane < 49) ? __expf(logit - mx) : 0.f;
    float s = e;
    #pragma unroll
    for (int d = 1; d < 64; d <<= 1) s += __shfl_xor(s, d);
    float wa = e / s;

    float2 o = {0.f, 0.f};
    #pragma unroll
    for (int tt = 0; tt < 49; ++tt) {
        int aa = tt / 7, kk2 = tt - aa * 7;
        const float2* vp = (const float2*)(v + (size_t)(pbase + aa * Ww + kk2) * CMID);
        float aw = __shfl(wa, tt);
        float2 vv = vp[lane];
        o.x = fmaf(aw, vv.x, o.x);
        o.y = fmaf(aw, vv.y, o.y);
    }
    size_t ob = ((size_t)(b * CMID + 2 * lane)) * HW + i * Ww + j;
    out[ob]      = o.x;
    out[ob + HW] = o.y;
}

extern "C" void kernel_launch(void* const* d_in, const int* in_sizes, int n_in,
                              void* d_out, int out_size, void* d_ws, size_t ws_size,
                              hipStream_t stream) {
    const float* x      = (const float*)d_in[0];
    const float* gn_w   = (const float*)d_in[1];
    const float* gn_b   = (const float*)d_in[2];
    const float* conv_w = (const float*)d_in[3];
    const float* conv_b = (const float*)d_in[4];
    const float* q_w    = (const float*)d_in[5];
    const float* q_b    = (const float*)d_in[6];
    const float* k_w    = (const float*)d_in[7];
    const float* k_b    = (const float*)d_in[8];
    const float* v_w    = (const float*)d_in[9];
    const float* v_b    = (const float*)d_in[10];

    float* ws    = (float*)d_ws;
    float* stats = ws;                        // 64 floats
    float* f     = ws + 64;                   // 2,359,296 (NHWC)
    float* qb_   = f   + (size_t)2 * CMID * HW;
    float* kb_   = qb_ + (size_t)2 * CMID * HW;
    float* vb_   = kb_ + (size_t)2 * CMID * HW;
    float* cwT   = qb_;   // alias: wt output lives in q-region until conv done;
                          // qkv overwrites it afterwards (stream-ordered, safe)

    gn_stats_kernel<<<32, 1024, 0, stream>>>(x, stats);
    wt_kernel<<<288, 256, 0, stream>>>(conv_w, cwT);
    conv_kernel<<<1152, 256, 0, stream>>>(x, stats, gn_w, gn_b, cwT, conv_b, f);
    qkv_kernel<<<864, 256, 0, stream>>>(f, q_w, q_b, k_w, k_b, v_w, v_b,
                                        qb_, kb_, vb_);
    nat_kernel<<<4608, 256, 0, stream>>>(qb_, kb_, vb_, (float*)d_out);
}

// Round 5
// 246.450 us; speedup vs baseline: 2.6341x; 1.0467x over previous
//
#include <hip/hip_runtime.h>
#include <math.h>

#define Hh 96
#define Ww 96
#define HW 9216
#define CIN 64
#define CMID 128
#define NAT_SCALE 11.313708498984761f   // sqrt(128), multiplies logits

// ---------- GN stats: one block per (batch, group), mean+rstd only ----------
__global__ __launch_bounds__(1024) void gn_stats_kernel(const float* __restrict__ x,
    float* __restrict__ stats)
{
    int blk = blockIdx.x;                  // b*16+g ; channels g*4..g*4+3
    int tid = threadIdx.x;
    size_t base = (size_t)blk * (4 * HW);
    float s = 0.f, s2 = 0.f;
    for (int idx = tid; idx < 4 * HW; idx += 1024) {
        float v = x[base + idx];
        s += v; s2 += v * v;
    }
    #pragma unroll
    for (int d = 1; d < 64; d <<= 1) {
        s  += __shfl_xor(s, d);
        s2 += __shfl_xor(s2, d);
    }
    __shared__ float as[16], as2[16];
    int wid = tid >> 6, lane = tid & 63;
    if (lane == 0) { as[wid] = s; as2[wid] = s2; }
    __syncthreads();
    if (tid == 0) {
        float S = 0.f, S2 = 0.f;
        #pragma unroll
        for (int w = 0; w < 16; ++w) { S += as[w]; S2 += as2[w]; }
        const float invN = 1.f / (float)(4 * HW);
        float mean = S * invN;
        float var  = S2 * invN - mean * mean;
        stats[blk * 2]     = mean;
        stats[blk * 2 + 1] = rsqrtf(var + 1e-5f);
    }
}

// ---------- conv-weight transpose: [oc][c*9+k9] -> [c*9+k9][oc] ----------
__global__ __launch_bounds__(256) void wt_kernel(const float* __restrict__ cw,
    float* __restrict__ cwT)
{
    int t = blockIdx.x * 256 + threadIdx.x;   // 73728 total
    int oc = t & 127, ck = t >> 7;            // ck = c*9+k9
    cwT[t] = cw[oc * 576 + ck];
}

// ---- QKV-weight repack: W[oc][c] -> wT4[m][c>>2][oc][c&3] (float4-friendly) ----
__global__ __launch_bounds__(256) void wq_kernel(const float* __restrict__ qw,
    const float* __restrict__ kw_, const float* __restrict__ vw,
    float* __restrict__ wt4)
{
    int t = blockIdx.x * 256 + threadIdx.x;   // 3*16384 = 49152 total
    int m = t >> 14, r = t & 16383;
    int c4 = r >> 9, oc = (r >> 2) & 127, cl = r & 3;
    const float* W = (m == 0) ? qw : (m == 1) ? kw_ : vw;
    wt4[t] = W[oc * CMID + c4 * 4 + cl];
}

// --- 3x3 conv + GN-on-the-fly + bias + exact GELU; lane = output channel ---
__global__ __launch_bounds__(256) void conv_kernel(const float* __restrict__ x,
    const float* __restrict__ stats,
    const float* __restrict__ gw, const float* __restrict__ gb,
    const float* __restrict__ cwT, const float* __restrict__ cb,
    float* __restrict__ f)
{
    __shared__ float tin[CIN * 48];          // [c][4 rows][12 cols] 12.3KB
    int bid = blockIdx.x;
    int swz = (bid & 7) * 144 + (bid >> 3);  // 1152 = 8*144, bijective
    int b = swz / 576, rem = swz - b * 576;
    int rp = rem / 12, cx = rem - rp * 12;
    int y0 = rp * 2, x0 = cx * 8;
    int tid = threadIdx.x;

    #pragma unroll
    for (int i = 0; i < 10; ++i) {           // stage 64c x 4x10 patch + GN
        int idx = tid + i * 256;
        int c = idx / 40, r2 = idx - c * 40;
        int ry = r2 / 10, rx = r2 - ry * 10;
        int gy = y0 - 1 + ry, gx = x0 - 1 + rx;
        float val = 0.f;
        if (gy >= 0 && gy < Hh && gx >= 0 && gx < Ww) {
            float xv = x[((size_t)(b * CIN + c)) * HW + gy * Ww + gx];
            int sg = (b * 16 + (c >> 2)) * 2;
            val = (xv - stats[sg]) * stats[sg + 1] * gw[c] + gb[c];
        }
        tin[c * 48 + ry * 12 + rx] = val;
    }
    __syncthreads();

    int wid = tid >> 6, lane = tid & 63;
    int oc = (wid & 1) * 64 + lane;
    int r = wid >> 1;

    float acc[8];
    float bias = cb[oc];
    #pragma unroll
    for (int p = 0; p < 8; ++p) acc[p] = bias;

    #pragma unroll 2
    for (int c = 0; c < CIN; ++c) {
        float wv[9];
        #pragma unroll
        for (int k9 = 0; k9 < 9; ++k9)
            wv[k9] = cwT[(c * 9 + k9) * 128 + oc];
        #pragma unroll
        for (int kh = 0; kh < 3; ++kh) {
            float xr[10];
            #pragma unroll
            for (int q4 = 0; q4 < 10; ++q4)
                xr[q4] = tin[c * 48 + (r + kh) * 12 + q4];
            #pragma unroll
            for (int kw = 0; kw < 3; ++kw)
                #pragma unroll
                for (int p = 0; p < 8; ++p)
                    acc[p] = fmaf(wv[kh * 3 + kw], xr[p + kw], acc[p]);
        }
    }

    int prow = (y0 + r) * Ww + x0;
    #pragma unroll
    for (int p = 0; p < 8; ++p) {
        float v = acc[p];
        float g = 0.5f * v * (1.f + erff(v * 0.70710678118654752f));
        f[((size_t)(b * HW + prow + p)) * CMID + oc] = g;   // NHWC, coalesced
    }
}

// ----- 1x1 QKV v4: lane = oc, f via scalar loads, no LDS -----
// grid = 3m x 576 pos-blocks(32); block = 4 waves = (2 posg x 2 oc-half)
__global__ __launch_bounds__(256) void qkv_kernel(const float* __restrict__ f,
    const float* __restrict__ wt4,
    const float* __restrict__ qb, const float* __restrict__ kb,
    const float* __restrict__ vb,
    float* __restrict__ qo, float* __restrict__ ko, float* __restrict__ vo)
{
    int bid = blockIdx.x;
    int swz = (bid & 7) * 216 + (bid >> 3);  // 1728 = 8*216, bijective
    int m = swz / 576, rem = swz - m * 576;
    int p0 = rem * 32;                       // global position base (b folded)
    int tid = threadIdx.x, wid = tid >> 6, lane = tid & 63;
    int posg = __builtin_amdgcn_readfirstlane(p0 + (wid >> 1) * 16); // uniform
    int oc = (wid & 1) * 64 + lane;

    const float4* Wt = (const float4*)(wt4 + (size_t)m * 16384);
    const float* Bm = (m == 0) ? qb : (m == 1) ? kb : vb;
    float*       Om = (m == 0) ? qo : (m == 1) ? ko : vo;

    float acc[16];
    float bias = Bm[oc];
    #pragma unroll
    for (int p = 0; p < 16; ++p) acc[p] = bias;

    #pragma unroll 2
    for (int c0 = 0; c0 < CMID; c0 += 16) {
        float4 wv[4];                        // per-lane weights, coalesced
        #pragma unroll
        for (int k = 0; k < 4; ++k)
            wv[k] = Wt[((c0 >> 2) + k) * 128 + oc];
        #pragma unroll
        for (int p = 0; p < 16; ++p) {
            // uniform addresses -> scalar loads (s_load_dwordx4/x16)
            const float4* fr = (const float4*)(f + (size_t)(posg + p) * CMID + c0);
            float4 f0 = fr[0], f1 = fr[1], f2 = fr[2], f3 = fr[3];
            float a = acc[p];
            a = fmaf(f0.x, wv[0].x, a); a = fmaf(f0.y, wv[0].y, a);
            a = fmaf(f0.z, wv[0].z, a); a = fmaf(f0.w, wv[0].w, a);
            a = fmaf(f1.x, wv[1].x, a); a = fmaf(f1.y, wv[1].y, a);
            a = fmaf(f1.z, wv[1].z, a); a = fmaf(f1.w, wv[1].w, a);
            a = fmaf(f2.x, wv[2].x, a); a = fmaf(f2.y, wv[2].y, a);
            a = fmaf(f2.z, wv[2].z, a); a = fmaf(f2.w, wv[2].w, a);
            a = fmaf(f3.x, wv[3].x, a); a = fmaf(f3.y, wv[3].y, a);
            a = fmaf(f3.z, wv[3].z, a); a = fmaf(f3.w, wv[3].w, a);
            acc[p] = a;
        }
    }

    #pragma unroll
    for (int p = 0; p < 16; ++p)
        Om[(size_t)(posg + p) * CMID + oc] = acc[p];   // 256B coalesced
}

// -------- 7x7 NAT: one wave/query; lane t computes logit t --------
__global__ __launch_bounds__(256) void nat_kernel(const float* __restrict__ q,
    const float* __restrict__ k, const float* __restrict__ v,
    float* __restrict__ out)
{
    int bid = blockIdx.x;
    int swz = (bid & 7) * 576 + (bid >> 3);  // 4608 = 8*576
    int tid = threadIdx.x;
    int wid = tid >> 6, lane = tid & 63;
    int qidx = __builtin_amdgcn_readfirstlane(swz * 4 + wid);
    int b = qidx / HW, r = qidx - b * HW;
    int i = r / Ww, j = r - i * Ww;
    int si = i - 3; si = si < 0 ? 0 : (si > Hh - 7 ? Hh - 7 : si);
    int sj = j - 3; sj = sj < 0 ? 0 : (sj > Ww - 7 ? Ww - 7 : sj);
    int pbase = b * HW + si * Ww + sj;

    int t = lane < 49 ? lane : 48;
    int a = t / 7, kk = t - a * 7;
    const float4* kp = (const float4*)(k + (size_t)(pbase + a * Ww + kk) * CMID);
    const float4* qp = (const float4*)(q + (size_t)qidx * CMID);
    float acc = 0.f;
    #pragma unroll 8
    for (int c = 0; c < 32; ++c) {
        float4 kv = kp[c];
        float4 qv = qp[c];
        acc = fmaf(qv.x, kv.x, acc);
        acc = fmaf(qv.y, kv.y, acc);
        acc = fmaf(qv.z, kv.z, acc);
        acc = fmaf(qv.w, kv.w, acc);
    }
    float logit = (lane < 49) ? acc * NAT_SCALE : -INFINITY;

    float mx = logit;
    #pragma unroll
    for (int d = 1; d < 64; d <<= 1) mx = fmaxf(mx, __shfl_xor(mx, d));
    float e = (lane < 49) ? __expf(logit - mx) : 0.f;
    float s = e;
    #pragma unroll
    for (int d = 1; d < 64; d <<= 1) s += __shfl_xor(s, d);
    float wa = e / s;

    float2 o = {0.f, 0.f};
    #pragma unroll
    for (int tt = 0; tt < 49; ++tt) {
        int aa = tt / 7, kk2 = tt - aa * 7;
        const float2* vp = (const float2*)(v + (size_t)(pbase + aa * Ww + kk2) * CMID);
        float aw = __shfl(wa, tt);
        float2 vv = vp[lane];
        o.x = fmaf(aw, vv.x, o.x);
        o.y = fmaf(aw, vv.y, o.y);
    }
    size_t ob = ((size_t)(b * CMID + 2 * lane)) * HW + i * Ww + j;
    out[ob]      = o.x;
    out[ob + HW] = o.y;
}

extern "C" void kernel_launch(void* const* d_in, const int* in_sizes, int n_in,
                              void* d_out, int out_size, void* d_ws, size_t ws_size,
                              hipStream_t stream) {
    const float* x      = (const float*)d_in[0];
    const float* gn_w   = (const float*)d_in[1];
    const float* gn_b   = (const float*)d_in[2];
    const float* conv_w = (const float*)d_in[3];
    const float* conv_b = (const float*)d_in[4];
    const float* q_w    = (const float*)d_in[5];
    const float* q_b    = (const float*)d_in[6];
    const float* k_w    = (const float*)d_in[7];
    const float* k_b    = (const float*)d_in[8];
    const float* v_w    = (const float*)d_in[9];
    const float* v_b    = (const float*)d_in[10];

    float* ws    = (float*)d_ws;
    float* stats = ws;                        // 64 floats
    float* f     = ws + 64;                   // 2,359,296 (NHWC)
    float* qb_   = f   + (size_t)2 * CMID * HW;
    float* kb_   = qb_ + (size_t)2 * CMID * HW;
    float* vb_   = kb_ + (size_t)2 * CMID * HW;
    float* cwT   = qb_;          // alias: conv weights live in q-region until
                                 // conv done; qkv overwrites afterwards (safe)
    float* wt4   = (float*)d_out; // alias: qkv weights in d_out; nat
                                  // fully overwrites d_out afterwards (safe)

    gn_stats_kernel<<<32, 1024, 0, stream>>>(x, stats);
    wt_kernel<<<288, 256, 0, stream>>>(conv_w, cwT);
    wq_kernel<<<192, 256, 0, stream>>>(q_w, k_w, v_w, wt4);
    conv_kernel<<<1152, 256, 0, stream>>>(x, stats, gn_w, gn_b, cwT, conv_b, f);
    qkv_kernel<<<1728, 256, 0, stream>>>(f, wt4, q_b, k_b, v_b, qb_, kb_, vb_);
    nat_kernel<<<4608, 256, 0, stream>>>(qb_, kb_, vb_, (float*)d_out);
}

// Round 6
// 142.566 us; speedup vs baseline: 4.5535x; 1.7287x over previous
//
#include <hip/hip_runtime.h>
#include <math.h>

#define Hh 96
#define Ww 96
#define HW 9216
#define CIN 64
#define CMID 128
#define NAT_SCALE 11.313708498984761f   // sqrt(128), multiplies logits

// ---------- GN stats: one block per (batch, group), mean+rstd only ----------
__global__ __launch_bounds__(1024) void gn_stats_kernel(const float* __restrict__ x,
    float* __restrict__ stats)
{
    int blk = blockIdx.x;                  // b*16+g ; channels g*4..g*4+3
    int tid = threadIdx.x;
    size_t base = (size_t)blk * (4 * HW);
    float s = 0.f, s2 = 0.f;
    for (int idx = tid; idx < 4 * HW; idx += 1024) {
        float v = x[base + idx];
        s += v; s2 += v * v;
    }
    #pragma unroll
    for (int d = 1; d < 64; d <<= 1) {
        s  += __shfl_xor(s, d);
        s2 += __shfl_xor(s2, d);
    }
    __shared__ float as[16], as2[16];
    int wid = tid >> 6, lane = tid & 63;
    if (lane == 0) { as[wid] = s; as2[wid] = s2; }
    __syncthreads();
    if (tid == 0) {
        float S = 0.f, S2 = 0.f;
        #pragma unroll
        for (int w = 0; w < 16; ++w) { S += as[w]; S2 += as2[w]; }
        const float invN = 1.f / (float)(4 * HW);
        float mean = S * invN;
        float var  = S2 * invN - mean * mean;
        stats[blk * 2]     = mean;
        stats[blk * 2 + 1] = rsqrtf(var + 1e-5f);
    }
}

// ---------- conv-weight transpose: [oc][c*9+k9] -> [c*9+k9][oc] ----------
__global__ __launch_bounds__(256) void wt_kernel(const float* __restrict__ cw,
    float* __restrict__ cwT)
{
    int t = blockIdx.x * 256 + threadIdx.x;   // 73728 total
    int oc = t & 127, ck = t >> 7;
    cwT[t] = cw[oc * 576 + ck];
}

// ---- QKV-weight repack: W[oc][c] -> wt4[m][c>>2][oc][c&3] ----
__global__ __launch_bounds__(256) void wq_kernel(const float* __restrict__ qw,
    const float* __restrict__ kw_, const float* __restrict__ vw,
    float* __restrict__ wt4)
{
    int t = blockIdx.x * 256 + threadIdx.x;   // 3*16384 = 49152 total
    int m = t >> 14, r = t & 16383;
    int c4 = r >> 9, oc = (r >> 2) & 127, cl = r & 3;
    const float* W = (m == 0) ? qw : (m == 1) ? kw_ : vw;
    wt4[t] = W[oc * CMID + c4 * 4 + cl];
}

// --- fused: GN-apply + 3x3 conv + GELU + 1x1 QKV; block = 2x8 pos x 128 oc ---
__global__ __launch_bounds__(256) void convqkv_kernel(const float* __restrict__ x,
    const float* __restrict__ stats,
    const float* __restrict__ gw, const float* __restrict__ gb,
    const float* __restrict__ cwT, const float* __restrict__ cb,
    const float* __restrict__ wt4,
    const float* __restrict__ qbias, const float* __restrict__ kbias,
    const float* __restrict__ vbias,
    float* __restrict__ qo, float* __restrict__ ko, float* __restrict__ vo)
{
    __shared__ float tin[CIN * 48];          // [c][4 rows][12 cols] 12.3KB
    __shared__ float fP[16][CMID];           // f tile [pos][c], 8KB
    int bid = blockIdx.x;
    int swz = (bid & 7) * 144 + (bid >> 3);  // 1152 = 8*144, bijective
    int b = swz / 576, rem = swz - b * 576;
    int rp = rem / 12, cx = rem - rp * 12;
    int y0 = rp * 2, x0 = cx * 8;
    int tid = threadIdx.x;

    #pragma unroll
    for (int i = 0; i < 10; ++i) {           // stage 64c x 4x10 patch + GN
        int idx = tid + i * 256;
        int c = idx / 40, r2 = idx - c * 40;
        int ry = r2 / 10, rx = r2 - ry * 10;
        int gy = y0 - 1 + ry, gx = x0 - 1 + rx;
        float val = 0.f;
        if (gy >= 0 && gy < Hh && gx >= 0 && gx < Ww) {
            float xv = x[((size_t)(b * CIN + c)) * HW + gy * Ww + gx];
            int sg = (b * 16 + (c >> 2)) * 2;
            val = (xv - stats[sg]) * stats[sg + 1] * gw[c] + gb[c];
        }
        tin[c * 48 + ry * 12 + rx] = val;
    }
    __syncthreads();

    int wid = tid >> 6, lane = tid & 63;
    int oc = (wid & 1) * 64 + lane;          // waves split oc halves
    int r = wid >> 1;                        // row 0/1 of the 2x8 tile

    float acc[8];
    float bias = cb[oc];
    #pragma unroll
    for (int p = 0; p < 8; ++p) acc[p] = bias;

    #pragma unroll 2
    for (int c = 0; c < CIN; ++c) {
        float wv[9];
        #pragma unroll
        for (int k9 = 0; k9 < 9; ++k9)
            wv[k9] = cwT[(c * 9 + k9) * 128 + oc];
        #pragma unroll
        for (int kh = 0; kh < 3; ++kh) {
            float xr[10];
            #pragma unroll
            for (int q4 = 0; q4 < 10; ++q4)
                xr[q4] = tin[c * 48 + (r + kh) * 12 + q4];
            #pragma unroll
            for (int kw = 0; kw < 3; ++kw)
                #pragma unroll
                for (int p = 0; p < 8; ++p)
                    acc[p] = fmaf(wv[kh * 3 + kw], xr[p + kw], acc[p]);
        }
    }

    #pragma unroll
    for (int p = 0; p < 8; ++p) {            // GELU -> LDS (lane=oc: conflict-free)
        float v = acc[p];
        fP[r * 8 + p][oc] = 0.5f * v * (1.f + erff(v * 0.70710678118654752f));
    }
    __syncthreads();

    // ---- QKV phase: wave = (pos-octet, oc-half); 3 m accumulated together ----
    int pw = (wid >> 1) * 8;                 // local positions pw..pw+7
    float aq[8], ak[8], av[8];
    float bq = qbias[oc], bk = kbias[oc], bv = vbias[oc];
    #pragma unroll
    for (int p = 0; p < 8; ++p) { aq[p] = bq; ak[p] = bk; av[p] = bv; }

    const float4* Wt = (const float4*)wt4;   // [m*4096 + c4*128 + oc]
    #pragma unroll 4
    for (int c0 = 0; c0 < CMID; c0 += 8) {
        int c4 = c0 >> 2;
        float4 wq0 = Wt[c4 * 128 + oc],        wq1 = Wt[(c4 + 1) * 128 + oc];
        float4 wk0 = Wt[4096 + c4 * 128 + oc], wk1 = Wt[4096 + (c4 + 1) * 128 + oc];
        float4 wv0 = Wt[8192 + c4 * 128 + oc], wv1 = Wt[8192 + (c4 + 1) * 128 + oc];
        #pragma unroll
        for (int p = 0; p < 8; ++p) {
            const float4* fr = (const float4*)&fP[pw + p][c0];
            float4 f0 = fr[0], f1 = fr[1];   // uniform broadcast ds_read_b128
            float q_ = aq[p], k_ = ak[p], v_ = av[p];
            q_ = fmaf(f0.x, wq0.x, q_); q_ = fmaf(f0.y, wq0.y, q_);
            q_ = fmaf(f0.z, wq0.z, q_); q_ = fmaf(f0.w, wq0.w, q_);
            q_ = fmaf(f1.x, wq1.x, q_); q_ = fmaf(f1.y, wq1.y, q_);
            q_ = fmaf(f1.z, wq1.z, q_); q_ = fmaf(f1.w, wq1.w, q_);
            k_ = fmaf(f0.x, wk0.x, k_); k_ = fmaf(f0.y, wk0.y, k_);
            k_ = fmaf(f0.z, wk0.z, k_); k_ = fmaf(f0.w, wk0.w, k_);
            k_ = fmaf(f1.x, wk1.x, k_); k_ = fmaf(f1.y, wk1.y, k_);
            k_ = fmaf(f1.z, wk1.z, k_); k_ = fmaf(f1.w, wk1.w, k_);
            v_ = fmaf(f0.x, wv0.x, v_); v_ = fmaf(f0.y, wv0.y, v_);
            v_ = fmaf(f0.z, wv0.z, v_); v_ = fmaf(f0.w, wv0.w, v_);
            v_ = fmaf(f1.x, wv1.x, v_); v_ = fmaf(f1.y, wv1.y, v_);
            v_ = fmaf(f1.z, wv1.z, v_); v_ = fmaf(f1.w, wv1.w, v_);
            aq[p] = q_; ak[p] = k_; av[p] = v_;
        }
    }

    int prow2 = (y0 + (pw >> 3)) * Ww + x0;
    #pragma unroll
    for (int p = 0; p < 8; ++p) {
        size_t gp = (size_t)(b * HW + prow2 + p) * CMID + oc;
        qo[gp] = aq[p]; ko[gp] = ak[p]; vo[gp] = av[p];   // 256B coalesced
    }
}

// ---- 7x7 NAT v3: one wave per 2x2 query group; lane = union-window row ----
__global__ __launch_bounds__(256) void nat_kernel(const float* __restrict__ q,
    const float* __restrict__ k, const float* __restrict__ v,
    float* __restrict__ out)
{
    int bid = blockIdx.x;
    int swz = (bid & 7) * 144 + (bid >> 3);  // 1152 = 8*144, bijective
    int tid = threadIdx.x;
    int wid = tid >> 6, lane = tid & 63;
    int g = __builtin_amdgcn_readfirstlane(swz * 4 + wid);  // 0..4607
    int b = g / 2304, rem = g - b * 2304;
    int ti = rem / 48, tj = rem - ti * 48;
    int i0 = ti * 2, j0 = tj * 2;

    int si0 = i0 - 3; si0 = si0 < 0 ? 0 : (si0 > 89 ? 89 : si0);
    int si1 = i0 - 2; si1 = si1 < 0 ? 0 : (si1 > 89 ? 89 : si1);
    int sj0 = j0 - 3; sj0 = sj0 < 0 ? 0 : (sj0 > 89 ? 89 : sj0);
    int sj1 = j0 - 2; sj1 = sj1 < 0 ? 0 : (sj1 > 89 ? 89 : sj1);
    int ui = si0 > 88 ? 88 : si0;
    int uj = sj0 > 88 ? 88 : sj0;
    int oi0 = si0 - ui, oi1 = si1 - ui, oj0 = sj0 - uj, oj1 = sj1 - uj;
    int base2 = b * HW + ui * Ww + uj;       // uniform union-window base

    int wr = lane >> 3, wc = lane & 7;       // lane's key position in 8x8 union

    // ---- phase 1: gather each K row once, dot against all 4 queries ----
    const float4* kp  = (const float4*)(k + (size_t)(base2 + wr * Ww + wc) * CMID);
    const float4* qp0 = (const float4*)(q + (size_t)(b * HW + i0 * Ww + j0) * CMID);
    const float4* qp2 = (const float4*)(q + (size_t)(b * HW + (i0 + 1) * Ww + j0) * CMID);
    float a0 = 0.f, a1 = 0.f, a2 = 0.f, a3 = 0.f;
    #pragma unroll
    for (int c = 0; c < 32; ++c) {
        float4 kv = kp[c];
        float4 q0 = qp0[c], q1 = qp0[c + 32], q2 = qp2[c], q3 = qp2[c + 32];
        a0 = fmaf(q0.x, kv.x, a0); a0 = fmaf(q0.y, kv.y, a0);
        a0 = fmaf(q0.z, kv.z, a0); a0 = fmaf(q0.w, kv.w, a0);
        a1 = fmaf(q1.x, kv.x, a1); a1 = fmaf(q1.y, kv.y, a1);
        a1 = fmaf(q1.z, kv.z, a1); a1 = fmaf(q1.w, kv.w, a1);
        a2 = fmaf(q2.x, kv.x, a2); a2 = fmaf(q2.y, kv.y, a2);
        a2 = fmaf(q2.z, kv.z, a2); a2 = fmaf(q2.w, kv.w, a2);
        a3 = fmaf(q3.x, kv.x, a3); a3 = fmaf(q3.y, kv.y, a3);
        a3 = fmaf(q3.z, kv.z, a3); a3 = fmaf(q3.w, kv.w, a3);
    }

    // ---- phase 2: masked softmax per query (lane holds its row's logit) ----
    float l0 = ((unsigned)(wr - oi0) <= 6u && (unsigned)(wc - oj0) <= 6u) ? a0 * NAT_SCALE : -INFINITY;
    float l1 = ((unsigned)(wr - oi0) <= 6u && (unsigned)(wc - oj1) <= 6u) ? a1 * NAT_SCALE : -INFINITY;
    float l2 = ((unsigned)(wr - oi1) <= 6u && (unsigned)(wc - oj0) <= 6u) ? a2 * NAT_SCALE : -INFINITY;
    float l3 = ((unsigned)(wr - oi1) <= 6u && (unsigned)(wc - oj1) <= 6u) ? a3 * NAT_SCALE : -INFINITY;
    float m0 = l0, m1 = l1, m2 = l2, m3 = l3;
    #pragma unroll
    for (int d = 1; d < 64; d <<= 1) {
        m0 = fmaxf(m0, __shfl_xor(m0, d)); m1 = fmaxf(m1, __shfl_xor(m1, d));
        m2 = fmaxf(m2, __shfl_xor(m2, d)); m3 = fmaxf(m3, __shfl_xor(m3, d));
    }
    float e0 = __expf(l0 - m0), e1 = __expf(l1 - m1);
    float e2 = __expf(l2 - m2), e3 = __expf(l3 - m3);
    float s0 = e0, s1 = e1, s2 = e2, s3 = e3;
    #pragma unroll
    for (int d = 1; d < 64; d <<= 1) {
        s0 += __shfl_xor(s0, d); s1 += __shfl_xor(s1, d);
        s2 += __shfl_xor(s2, d); s3 += __shfl_xor(s3, d);
    }
    float w0 = e0 / s0, w1 = e1 / s1, w2 = e2 / s2, w3 = e3 / s3;

    // ---- phase 3: PV over the 64 shared rows; lane = channel pair ----
    const float2* vbase = (const float2*)(v + (size_t)base2 * CMID);
    float2 o0 = {0.f, 0.f}, o1 = {0.f, 0.f}, o2 = {0.f, 0.f}, o3 = {0.f, 0.f};
    #pragma unroll
    for (int w = 0; w < 64; ++w) {
        int off = ((w >> 3) * Ww + (w & 7)) * 64;   // float2 units
        float2 vv = vbase[off + lane];
        float b0 = __shfl(w0, w), b1 = __shfl(w1, w);
        float b2 = __shfl(w2, w), b3 = __shfl(w3, w);
        o0.x = fmaf(b0, vv.x, o0.x); o0.y = fmaf(b0, vv.y, o0.y);
        o1.x = fmaf(b1, vv.x, o1.x); o1.y = fmaf(b1, vv.y, o1.y);
        o2.x = fmaf(b2, vv.x, o2.x); o2.y = fmaf(b2, vv.y, o2.y);
        o3.x = fmaf(b3, vv.x, o3.x); o3.y = fmaf(b3, vv.y, o3.y);
    }

    size_t ob = ((size_t)(b * CMID + 2 * lane)) * HW + i0 * Ww + j0;
    float2 r0 = {o0.x, o1.x}, r1 = {o0.y, o1.y};
    float2 r2 = {o2.x, o3.x}, r3 = {o2.y, o3.y};
    *(float2*)(out + ob)           = r0;
    *(float2*)(out + ob + HW)      = r1;
    *(float2*)(out + ob + Ww)      = r2;
    *(float2*)(out + ob + HW + Ww) = r3;
}

extern "C" void kernel_launch(void* const* d_in, const int* in_sizes, int n_in,
                              void* d_out, int out_size, void* d_ws, size_t ws_size,
                              hipStream_t stream) {
    const float* x      = (const float*)d_in[0];
    const float* gn_w   = (const float*)d_in[1];
    const float* gn_b   = (const float*)d_in[2];
    const float* conv_w = (const float*)d_in[3];
    const float* conv_b = (const float*)d_in[4];
    const float* q_w    = (const float*)d_in[5];
    const float* q_b    = (const float*)d_in[6];
    const float* k_w    = (const float*)d_in[7];
    const float* k_b    = (const float*)d_in[8];
    const float* v_w    = (const float*)d_in[9];
    const float* v_b    = (const float*)d_in[10];

    float* ws    = (float*)d_ws;
    float* stats = ws;                        // 64 floats
    float* qb_   = ws + 64;                   // 3 x 2,359,296 (NHWC q,k,v)
    float* kb_   = qb_ + (size_t)2 * CMID * HW;
    float* vb_   = kb_ + (size_t)2 * CMID * HW;
    float* cwT   = vb_ + (size_t)2 * CMID * HW;  // 73,728
    float* wt4   = cwT + 73728;                  // 49,152

    gn_stats_kernel<<<32, 1024, 0, stream>>>(x, stats);
    wt_kernel<<<288, 256, 0, stream>>>(conv_w, cwT);
    wq_kernel<<<192, 256, 0, stream>>>(q_w, k_w, v_w, wt4);
    convqkv_kernel<<<1152, 256, 0, stream>>>(x, stats, gn_w, gn_b, cwT, conv_b,
                                             wt4, q_b, k_b, v_b, qb_, kb_, vb_);
    nat_kernel<<<1152, 256, 0, stream>>>(qb_, kb_, vb_, (float*)d_out);
}

// Round 8
// 109.101 us; speedup vs baseline: 5.9503x; 1.3067x over previous
//
#include <hip/hip_runtime.h>
#include <math.h>

#define Hh 96
#define Ww 96
#define HW 9216
#define CIN 64
#define CMID 128
#define NAT_SCALE 11.313708498984761f   // sqrt(128), multiplies logits

typedef __attribute__((ext_vector_type(4))) float f32x4;
typedef __attribute__((ext_vector_type(8))) short short8;

__device__ __forceinline__ unsigned short f2bf(float x) {
    union { float f; unsigned u; } v; v.f = x;
    unsigned r = v.u + 0x7FFF + ((v.u >> 16) & 1);     // RNE
    return (unsigned short)(r >> 16);
}
__device__ __forceinline__ float bf2f(unsigned short h) {
    union { unsigned u; float f; } v; v.u = (unsigned)h << 16;
    return v.f;
}

// ---------- GN stats: one block per (batch, group) ----------
__global__ __launch_bounds__(1024) void gn_stats_kernel(const float* __restrict__ x,
    float* __restrict__ stats)
{
    int blk = blockIdx.x;
    int tid = threadIdx.x;
    size_t base = (size_t)blk * (4 * HW);
    float s = 0.f, s2 = 0.f;
    for (int idx = tid; idx < 4 * HW; idx += 1024) {
        float v = x[base + idx];
        s += v; s2 += v * v;
    }
    #pragma unroll
    for (int d = 1; d < 64; d <<= 1) {
        s  += __shfl_xor(s, d);
        s2 += __shfl_xor(s2, d);
    }
    __shared__ float as[16], as2[16];
    int wid = tid >> 6, lane = tid & 63;
    if (lane == 0) { as[wid] = s; as2[wid] = s2; }
    __syncthreads();
    if (tid == 0) {
        float S = 0.f, S2 = 0.f;
        #pragma unroll
        for (int w = 0; w < 16; ++w) { S += as[w]; S2 += as2[w]; }
        const float invN = 1.f / (float)(4 * HW);
        float mean = S * invN;
        float var  = S2 * invN - mean * mean;
        stats[blk * 2]     = mean;
        stats[blk * 2 + 1] = rsqrtf(var + 1e-5f);
    }
}

// ---- GN-apply -> padded NHWC bf16 hi/lo planes [b][98][98][64] ----
__global__ __launch_bounds__(256) void gnapply_kernel(const float* __restrict__ x,
    const float* __restrict__ stats,
    const float* __restrict__ gw, const float* __restrict__ gb,
    unsigned short* __restrict__ xh, unsigned short* __restrict__ xl)
{
    __shared__ float tin[64 * 97];
    int blk = blockIdx.x;                    // b*96 + y
    int b = blk / 96, y = blk - b * 96;
    int tid = threadIdx.x;
    #pragma unroll
    for (int i = 0; i < 24; ++i) {
        int idx = i * 256 + tid;             // 6144 = 64c x 96x
        int c = idx / 96, xx = idx - c * 96;
        float v = x[((size_t)(b * CIN + c)) * HW + y * Ww + xx];
        int sg = (b * 16 + (c >> 2)) * 2;
        tin[c * 97 + xx] = (v - stats[sg]) * stats[sg + 1] * gw[c] + gb[c];
    }
    __syncthreads();
    #pragma unroll
    for (int i = 0; i < 24; ++i) {
        int idx = i * 256 + tid;
        int xx = idx >> 6, c = idx & 63;
        float v = tin[c * 97 + xx];
        unsigned short hi = f2bf(v);
        unsigned short lo = f2bf(v - bf2f(hi));
        size_t dst = ((size_t)(b * 98 + y + 1) * 98 + xx + 1) * 64 + c;
        xh[dst] = hi; xl[dst] = lo;
    }
}

// ---- conv weights [oc][c*9+k9] -> bf16 hi/lo [oc][k9*64+c] ----
__global__ __launch_bounds__(256) void wtc_kernel(const float* __restrict__ cw,
    unsigned short* __restrict__ wh, unsigned short* __restrict__ wl)
{
    int t = blockIdx.x * 256 + threadIdx.x;   // 73728
    int oc = t / 576, kk = t - oc * 576;
    int k9 = kk >> 6, c = kk & 63;
    float v = cw[oc * 576 + c * 9 + k9];
    unsigned short hi = f2bf(v);
    wh[t] = hi; wl[t] = f2bf(v - bf2f(hi));
}

// ---- qkv weights -> bf16 hi/lo [m][oc][c] ----
__global__ __launch_bounds__(256) void wq_kernel(const float* __restrict__ qw,
    const float* __restrict__ kw_, const float* __restrict__ vw,
    unsigned short* __restrict__ wh, unsigned short* __restrict__ wl)
{
    int t = blockIdx.x * 256 + threadIdx.x;   // 49152
    int m = t >> 14, r = t & 16383;
    const float* W = (m == 0) ? qw : (m == 1) ? kw_ : vw;
    float v = W[r];
    unsigned short hi = f2bf(v);
    wh[t] = hi; wl[t] = f2bf(v - bf2f(hi));
}

#define MFMA3(ACC, AH, AL, BH, BL) \
    ACC = __builtin_amdgcn_mfma_f32_16x16x32_bf16(AL, BH, ACC, 0, 0, 0); \
    ACC = __builtin_amdgcn_mfma_f32_16x16x32_bf16(AH, BL, ACC, 0, 0, 0); \
    ACC = __builtin_amdgcn_mfma_f32_16x16x32_bf16(AH, BH, ACC, 0, 0, 0);

// --- fused MFMA (bf16x3 split): 3x3 conv + GELU + QKV GEMM ---
// block = 4x8 positions x 128 oc; 4 waves, each 32pos x 32oc via 2x2 16x16x32
__global__ __launch_bounds__(256) void convqkv_kernel(
    const unsigned short* __restrict__ xh, const unsigned short* __restrict__ xl,
    const unsigned short* __restrict__ wch, const unsigned short* __restrict__ wcl,
    const float* __restrict__ cb,
    const unsigned short* __restrict__ wqh, const unsigned short* __restrict__ wql,
    const float* __restrict__ qbias, const float* __restrict__ kbias,
    const float* __restrict__ vbias,
    float* __restrict__ qo, float* __restrict__ ko, float* __restrict__ vo)
{
    __shared__ __align__(16) short ph_s[3840];   // [6r][10c][64ch] swizzled, hi
    __shared__ __align__(16) short pl_s[3840];   // lo
    __shared__ __align__(16) short fh_s[4096];   // [32 pos][128 c] swizzled, hi
    __shared__ __align__(16) short fl_s[4096];   // lo
    int bid = blockIdx.x;
    int swz = (bid & 7) * 72 + (bid >> 3);   // 576 = 8*72, bijective
    int b = swz / 288, rem = swz - b * 288;
    int ty = rem / 12, tx = rem - ty * 12;
    int y0 = ty * 4, x0 = tx * 8;
    int tid = threadIdx.x;

    // stage 6x10x64 bf16 patch (hi+lo), 16B granules, XOR-swizzle by (col&7)
    for (int g = tid; g < 480; g += 256) {
        int row = g / 80, r2 = g - row * 80;
        int col = r2 >> 3, gc = r2 & 7;
        size_t srcoff = ((size_t)(b * 98 + y0 + row) * 98 + x0 + col) * 64 + gc * 8;
        int dst = ((row * 10 + col) << 6) + ((gc ^ (col & 7)) << 3);
        *(short8*)&ph_s[dst] = *(const short8*)(xh + srcoff);
        *(short8*)&pl_s[dst] = *(const short8*)(xl + srcoff);
    }
    __syncthreads();

    int wid = tid >> 6, l = tid & 63;
    int l15 = l & 15, l4 = l >> 4;
    int oc0 = wid * 32;
    int p0 = l15, p1 = 16 + l15;
    int r0 = p0 >> 3, xc = p0 & 7;

    f32x4 acc00 = {0.f,0.f,0.f,0.f}, acc01 = {0.f,0.f,0.f,0.f};
    f32x4 acc10 = {0.f,0.f,0.f,0.f}, acc11 = {0.f,0.f,0.f,0.f};

    #pragma unroll 3
    for (int s = 0; s < 9; ++s) {
        int dy = s / 3, dx = s - dy * 3;
        int colA = xc + dx, cswz = (colA & 7) << 3;
        #pragma unroll
        for (int ch = 0; ch < 2; ++ch) {
            int gr = (ch * 4 + l4) << 3;
            int a0i = (((r0 + dy) * 10 + colA) << 6) + (gr ^ cswz);
            int a1i = (((r0 + 2 + dy) * 10 + colA) << 6) + (gr ^ cswz);
            short8 a0h = *(const short8*)&ph_s[a0i];
            short8 a0l = *(const short8*)&pl_s[a0i];
            short8 a1h = *(const short8*)&ph_s[a1i];
            short8 a1l = *(const short8*)&pl_s[a1i];
            int k = s * 64 + ch * 32 + l4 * 8;
            short8 b0h = *(const short8*)(wch + (oc0 + l15) * 576 + k);
            short8 b0l = *(const short8*)(wcl + (oc0 + l15) * 576 + k);
            short8 b1h = *(const short8*)(wch + (oc0 + 16 + l15) * 576 + k);
            short8 b1l = *(const short8*)(wcl + (oc0 + 16 + l15) * 576 + k);
            MFMA3(acc00, a0h, a0l, b0h, b0l)
            MFMA3(acc01, a0h, a0l, b1h, b1l)
            MFMA3(acc10, a1h, a1l, b0h, b0l)
            MFMA3(acc11, a1h, a1l, b1h, b1l)
        }
    }

    // bias + exact GELU -> hi/lo bf16 -> swizzled f LDS
    float bias0 = cb[oc0 + l15], bias1 = cb[oc0 + 16 + l15];
    #pragma unroll
    for (int mf = 0; mf < 2; ++mf) {
        #pragma unroll
        for (int nf = 0; nf < 2; ++nf) {
            f32x4 a = (mf == 0) ? (nf == 0 ? acc00 : acc01) : (nf == 0 ? acc10 : acc11);
            float bs = nf == 0 ? bias0 : bias1;
            int oc = oc0 + nf * 16 + l15;
            #pragma unroll
            for (int rr = 0; rr < 4; ++rr) {
                int p = mf * 16 + l4 * 4 + rr;
                float v = a[rr] + bs;
                float g = 0.5f * v * (1.f + erff(v * 0.70710678118654752f));
                unsigned short hi = f2bf(g);
                unsigned short lo = f2bf(g - bf2f(hi));
                int di = p * 128 + ((((oc >> 3) ^ (p & 7)) << 3) | (oc & 7));
                fh_s[di] = (short)hi;
                fl_s[di] = (short)lo;
            }
        }
    }
    __syncthreads();

    // ---- QKV GEMM: A = f (shared by all 3 m), B = wq[m][oc][c] ----
    short8 aqh[4][2], aql[4][2];             // [kc2][mf]
    #pragma unroll
    for (int kc2 = 0; kc2 < 4; ++kc2) {
        int gr2 = (kc2 * 4 + l4) << 3;
        int i0 = p0 * 128 + (gr2 ^ ((p0 & 7) << 3));
        int i1 = p1 * 128 + (gr2 ^ ((p1 & 7) << 3));
        aqh[kc2][0] = *(const short8*)&fh_s[i0];
        aql[kc2][0] = *(const short8*)&fl_s[i0];
        aqh[kc2][1] = *(const short8*)&fh_s[i1];
        aql[kc2][1] = *(const short8*)&fl_s[i1];
    }

    #pragma unroll 1
    for (int m = 0; m < 3; ++m) {
        const unsigned short* Wh = wqh + m * 16384;
        const unsigned short* Wl = wql + m * 16384;
        const float* Bi = (m == 0) ? qbias : (m == 1) ? kbias : vbias;
        float* Om = (m == 0) ? qo : (m == 1) ? ko : vo;
        f32x4 c00 = {0.f,0.f,0.f,0.f}, c01 = {0.f,0.f,0.f,0.f};
        f32x4 c10 = {0.f,0.f,0.f,0.f}, c11 = {0.f,0.f,0.f,0.f};
        #pragma unroll
        for (int kc2 = 0; kc2 < 4; ++kc2) {
            int k = kc2 * 32 + l4 * 8;
            short8 b0h = *(const short8*)(Wh + (oc0 + l15) * 128 + k);
            short8 b0l = *(const short8*)(Wl + (oc0 + l15) * 128 + k);
            short8 b1h = *(const short8*)(Wh + (oc0 + 16 + l15) * 128 + k);
            short8 b1l = *(const short8*)(Wl + (oc0 + 16 + l15) * 128 + k);
            MFMA3(c00, aqh[kc2][0], aql[kc2][0], b0h, b0l)
            MFMA3(c01, aqh[kc2][0], aql[kc2][0], b1h, b1l)
            MFMA3(c10, aqh[kc2][1], aql[kc2][1], b0h, b0l)
            MFMA3(c11, aqh[kc2][1], aql[kc2][1], b1h, b1l)
        }
        float bm0 = Bi[oc0 + l15], bm1 = Bi[oc0 + 16 + l15];
        #pragma unroll
        for (int mf = 0; mf < 2; ++mf) {
            #pragma unroll
            for (int nf = 0; nf < 2; ++nf) {
                f32x4 a = (mf == 0) ? (nf == 0 ? c00 : c01) : (nf == 0 ? c10 : c11);
                float bs = nf == 0 ? bm0 : bm1;
                int oc = oc0 + nf * 16 + l15;
                #pragma unroll
                for (int rr = 0; rr < 4; ++rr) {
                    int p = mf * 16 + l4 * 4 + rr;
                    int yy = y0 + (p >> 3), xx = x0 + (p & 7);
                    Om[((size_t)(b * HW + yy * Ww + xx)) * CMID + oc] = a[rr] + bs;
                }
            }
        }
    }
}

// ---- 7x7 NAT: one wave per 2x2 query group; lane = union-window row ----
__global__ __launch_bounds__(256) void nat_kernel(const float* __restrict__ q,
    const float* __restrict__ k, const float* __restrict__ v,
    float* __restrict__ out)
{
    int bid = blockIdx.x;
    int swz = (bid & 7) * 144 + (bid >> 3);  // 1152 = 8*144, bijective
    int tid = threadIdx.x;
    int wid = tid >> 6, lane = tid & 63;
    int g = __builtin_amdgcn_readfirstlane(swz * 4 + wid);  // 0..4607
    int b = g / 2304, rem = g - b * 2304;
    int ti = rem / 48, tj = rem - ti * 48;
    int i0 = ti * 2, j0 = tj * 2;

    int si0 = i0 - 3; si0 = si0 < 0 ? 0 : (si0 > 89 ? 89 : si0);
    int si1 = i0 - 2; si1 = si1 < 0 ? 0 : (si1 > 89 ? 89 : si1);
    int sj0 = j0 - 3; sj0 = sj0 < 0 ? 0 : (sj0 > 89 ? 89 : sj0);
    int sj1 = j0 - 2; sj1 = sj1 < 0 ? 0 : (sj1 > 89 ? 89 : sj1);
    int ui = si0 > 88 ? 88 : si0;
    int uj = sj0 > 88 ? 88 : sj0;
    int oi0 = si0 - ui, oi1 = si1 - ui, oj0 = sj0 - uj, oj1 = sj1 - uj;
    int base2 = b * HW + ui * Ww + uj;

    int wr = lane >> 3, wc = lane & 7;

    const float4* kp  = (const float4*)(k + (size_t)(base2 + wr * Ww + wc) * CMID);
    const float4* qp0 = (const float4*)(q + (size_t)(b * HW + i0 * Ww + j0) * CMID);
    const float4* qp2 = (const float4*)(q + (size_t)(b * HW + (i0 + 1) * Ww + j0) * CMID);
    float a0 = 0.f, a1 = 0.f, a2 = 0.f, a3 = 0.f;
    #pragma unroll
    for (int c = 0; c < 32; ++c) {
        float4 kv = kp[c];
        float4 q0 = qp0[c], q1 = qp0[c + 32], q2 = qp2[c], q3 = qp2[c + 32];
        a0 = fmaf(q0.x, kv.x, a0); a0 = fmaf(q0.y, kv.y, a0);
        a0 = fmaf(q0.z, kv.z, a0); a0 = fmaf(q0.w, kv.w, a0);
        a1 = fmaf(q1.x, kv.x, a1); a1 = fmaf(q1.y, kv.y, a1);
        a1 = fmaf(q1.z, kv.z, a1); a1 = fmaf(q1.w, kv.w, a1);
        a2 = fmaf(q2.x, kv.x, a2); a2 = fmaf(q2.y, kv.y, a2);
        a2 = fmaf(q2.z, kv.z, a2); a2 = fmaf(q2.w, kv.w, a2);
        a3 = fmaf(q3.x, kv.x, a3); a3 = fmaf(q3.y, kv.y, a3);
        a3 = fmaf(q3.z, kv.z, a3); a3 = fmaf(q3.w, kv.w, a3);
    }

    float l0 = ((unsigned)(wr - oi0) <= 6u && (unsigned)(wc - oj0) <= 6u) ? a0 * NAT_SCALE : -INFINITY;
    float l1 = ((unsigned)(wr - oi0) <= 6u && (unsigned)(wc - oj1) <= 6u) ? a1 * NAT_SCALE : -INFINITY;
    float l2 = ((unsigned)(wr - oi1) <= 6u && (unsigned)(wc - oj0) <= 6u) ? a2 * NAT_SCALE : -INFINITY;
    float l3 = ((unsigned)(wr - oi1) <= 6u && (unsigned)(wc - oj1) <= 6u) ? a3 * NAT_SCALE : -INFINITY;
    float m0 = l0, m1 = l1, m2 = l2, m3 = l3;
    #pragma unroll
    for (int d = 1; d < 64; d <<= 1) {
        m0 = fmaxf(m0, __shfl_xor(m0, d)); m1 = fmaxf(m1, __shfl_xor(m1, d));
        m2 = fmaxf(m2, __shfl_xor(m2, d)); m3 = fmaxf(m3, __shfl_xor(m3, d));
    }
    float e0 = __expf(l0 - m0), e1 = __expf(l1 - m1);
    float e2 = __expf(l2 - m2), e3 = __expf(l3 - m3);
    float s0 = e0, s1 = e1, s2 = e2, s3 = e3;
    #pragma unroll
    for (int d = 1; d < 64; d <<= 1) {
        s0 += __shfl_xor(s0, d); s1 += __shfl_xor(s1, d);
        s2 += __shfl_xor(s2, d); s3 += __shfl_xor(s3, d);
    }
    float w0 = e0 / s0, w1 = e1 / s1, w2 = e2 / s2, w3 = e3 / s3;

    const float2* vbase = (const float2*)(v + (size_t)base2 * CMID);
    float2 o0 = {0.f, 0.f}, o1 = {0.f, 0.f}, o2 = {0.f, 0.f}, o3 = {0.f, 0.f};
    #pragma unroll
    for (int w = 0; w < 64; ++w) {
        int off = ((w >> 3) * Ww + (w & 7)) * 64;
        float2 vv = vbase[off + lane];
        float b0 = __shfl(w0, w), b1 = __shfl(w1, w);
        float b2 = __shfl(w2, w), b3 = __shfl(w3, w);
        o0.x = fmaf(b0, vv.x, o0.x); o0.y = fmaf(b0, vv.y, o0.y);
        o1.x = fmaf(b1, vv.x, o1.x); o1.y = fmaf(b1, vv.y, o1.y);
        o2.x = fmaf(b2, vv.x, o2.x); o2.y = fmaf(b2, vv.y, o2.y);
        o3.x = fmaf(b3, vv.x, o3.x); o3.y = fmaf(b3, vv.y, o3.y);
    }

    size_t ob = ((size_t)(b * CMID + 2 * lane)) * HW + i0 * Ww + j0;
    float2 r0 = {o0.x, o1.x}, r1 = {o0.y, o1.y};
    float2 r2 = {o2.x, o3.x}, r3 = {o2.y, o3.y};
    *(float2*)(out + ob)           = r0;
    *(float2*)(out + ob + HW)      = r1;
    *(float2*)(out + ob + Ww)      = r2;
    *(float2*)(out + ob + HW + Ww) = r3;
}

extern "C" void kernel_launch(void* const* d_in, const int* in_sizes, int n_in,
                              void* d_out, int out_size, void* d_ws, size_t ws_size,
                              hipStream_t stream) {
    const float* x      = (const float*)d_in[0];
    const float* gn_w   = (const float*)d_in[1];
    const float* gn_b   = (const float*)d_in[2];
    const float* conv_w = (const float*)d_in[3];
    const float* conv_b = (const float*)d_in[4];
    const float* q_w    = (const float*)d_in[5];
    const float* q_b    = (const float*)d_in[6];
    const float* k_w    = (const float*)d_in[7];
    const float* k_b    = (const float*)d_in[8];
    const float* v_w    = (const float*)d_in[9];
    const float* v_b    = (const float*)d_in[10];

    const size_t XNP = (size_t)2 * 98 * 98 * 64;      // 1,229,312 per plane
    float* ws    = (float*)d_ws;
    float* stats = ws;                                 // 64 floats
    float* qb_   = ws + 64;                            // 3 x 2,359,296 fp32 NHWC
    float* kb_   = qb_ + (size_t)2 * CMID * HW;
    float* vb_   = kb_ + (size_t)2 * CMID * HW;
    unsigned short* xnh = (unsigned short*)(vb_ + (size_t)2 * CMID * HW);
    unsigned short* xnl = xnh + XNP;
    unsigned short* wch = xnl + XNP;                   // 73,728 each
    unsigned short* wcl = wch + 73728;
    unsigned short* wqh = wcl + 73728;                 // 49,152 each
    unsigned short* wql = wqh + 49152;

    gn_stats_kernel<<<32, 1024, 0, stream>>>(x, stats);
    hipMemsetAsync(xnh, 0, XNP * 2 * sizeof(unsigned short), stream);
    gnapply_kernel<<<192, 256, 0, stream>>>(x, stats, gn_w, gn_b, xnh, xnl);
    wtc_kernel<<<288, 256, 0, stream>>>(conv_w, wch, wcl);
    wq_kernel<<<192, 256, 0, stream>>>(q_w, k_w, v_w, wqh, wql);
    convqkv_kernel<<<576, 256, 0, stream>>>(xnh, xnl, wch, wcl, conv_b,
                                            wqh, wql, q_b, k_b, v_b,
                                            qb_, kb_, vb_);
    nat_kernel<<<1152, 256, 0, stream>>>(qb_, kb_, vb_, (float*)d_out);
}

// Round 9
// 86.036 us; speedup vs baseline: 7.5455x; 1.2681x over previous
//
#include <hip/hip_runtime.h>
#include <math.h>

#define Hh 96
#define Ww 96
#define HW 9216
#define CIN 64
#define CMID 128
#define NAT_SCALE 11.313708498984761f   // sqrt(128), multiplies logits

typedef __attribute__((ext_vector_type(4))) float f32x4;
typedef __attribute__((ext_vector_type(8))) short short8;

__device__ __forceinline__ unsigned short f2bf(float x) {
    union { float f; unsigned u; } v; v.f = x;
    unsigned r = v.u + 0x7FFF + ((v.u >> 16) & 1);     // RNE
    return (unsigned short)(r >> 16);
}
__device__ __forceinline__ float bf2f(unsigned short h) {
    union { unsigned u; float f; } v; v.u = (unsigned)h << 16;
    return v.f;
}

// ---------- GN stats stage 1: 512 blocks, partial sums ----------
__global__ __launch_bounds__(256) void gn_partial_kernel(const float* __restrict__ x,
    float2* __restrict__ partials)
{
    int blk = blockIdx.x;                    // (b*16+g)*16 + sub
    int tid = threadIdx.x;
    size_t base = (size_t)(blk >> 4) * 36864 + (size_t)(blk & 15) * 2304;
    float s = 0.f, s2 = 0.f;
    #pragma unroll
    for (int i = 0; i < 9; ++i) {
        float v = x[base + i * 256 + tid];
        s += v; s2 += v * v;
    }
    #pragma unroll
    for (int d = 1; d < 64; d <<= 1) {
        s  += __shfl_xor(s, d);
        s2 += __shfl_xor(s2, d);
    }
    __shared__ float as[4], as2[4];
    int wid = tid >> 6, lane = tid & 63;
    if (lane == 0) { as[wid] = s; as2[wid] = s2; }
    __syncthreads();
    if (tid == 0) {
        float2 r = { as[0]+as[1]+as[2]+as[3], as2[0]+as2[1]+as2[2]+as2[3] };
        partials[blk] = r;
    }
}

// ---- GN-apply -> padded NHWC bf16 hi/lo planes [b][98][98][64] ----
// grid = 2b x 96y x 4 quarters; folds the stats finalize (reads partials)
__global__ __launch_bounds__(256) void gnapply_kernel(const float* __restrict__ x,
    const float2* __restrict__ partials,
    const float* __restrict__ gw, const float* __restrict__ gb,
    unsigned short* __restrict__ xh, unsigned short* __restrict__ xl)
{
    __shared__ float tin[64 * 25];           // [c][24+1]
    __shared__ float sgld[32];               // 16 groups x {mean, rstd}
    int blk = blockIdx.x;                    // b*384 + y*4 + q
    int b = blk / 384, r1 = blk - b * 384;
    int y = r1 >> 2, q = r1 & 3;
    int tid = threadIdx.x;

    if (tid < 256) {                         // finalize this batch's 16 groups
        float2 pv = partials[b * 256 + tid];
        float s = pv.x, s2 = pv.y;
        #pragma unroll
        for (int d = 1; d < 16; d <<= 1) {
            s  += __shfl_xor(s, d);
            s2 += __shfl_xor(s2, d);
        }
        if ((tid & 15) == 0) {
            const float invN = 1.f / 36864.f;
            float mean = s * invN;
            float var  = s2 * invN - mean * mean;
            sgld[(tid >> 4) * 2]     = mean;
            sgld[(tid >> 4) * 2 + 1] = rsqrtf(var + 1e-5f);
        }
    }
    #pragma unroll
    for (int i = 0; i < 6; ++i) {            // stage raw 64c x 24x
        int idx = i * 256 + tid;             // 1536
        int c = idx / 24, xx = idx - c * 24;
        tin[c * 25 + xx] = x[((size_t)(b * CIN + c)) * HW + y * Ww + q * 24 + xx];
    }
    __syncthreads();
    #pragma unroll
    for (int i = 0; i < 6; ++i) {
        int idx = i * 256 + tid;
        int xx = idx >> 6, c = idx & 63;
        float v = tin[c * 25 + xx];
        float val = (v - sgld[(c >> 2) * 2]) * sgld[(c >> 2) * 2 + 1] * gw[c] + gb[c];
        unsigned short hi = f2bf(val);
        unsigned short lo = f2bf(val - bf2f(hi));
        size_t dst = ((size_t)(b * 98 + y + 1) * 98 + q * 24 + xx + 1) * 64 + c;
        xh[dst] = hi; xl[dst] = lo;
    }
}

// ---- weight repack (conv + qkv), lane-exact coalesced layout ----
// conv: [s2(18)][ocg(4)][fr(2)][lane(64)][e(8)]  src cw[oc][c*9+s]
// qkv : [m(3)][kc2(4)][ocg(4)][fr(2)][lane(64)][e(8)]  src W[oc][c]
__global__ __launch_bounds__(256) void repack_kernel(const float* __restrict__ cw,
    const float* __restrict__ qw, const float* __restrict__ kw_,
    const float* __restrict__ vw,
    unsigned short* __restrict__ wch, unsigned short* __restrict__ wcl,
    unsigned short* __restrict__ wqh, unsigned short* __restrict__ wql)
{
    int t = blockIdx.x * 256 + threadIdx.x;  // 122880 total
    if (t < 73728) {
        int e = t & 7, l = (t >> 3) & 63, fr = (t >> 9) & 1;
        int ocg = (t >> 10) & 3, s2 = t >> 12;      // 0..17
        int s = s2 >> 1, ch = s2 & 1;
        int oc = ocg * 32 + fr * 16 + (l & 15);
        int c  = ch * 32 + (l >> 4) * 8 + e;
        float v = cw[oc * 576 + c * 9 + s];
        unsigned short hi = f2bf(v);
        wch[t] = hi; wcl[t] = f2bf(v - bf2f(hi));
    } else {
        int t2 = t - 73728;                  // < 49152
        int e = t2 & 7, l = (t2 >> 3) & 63, fr = (t2 >> 9) & 1;
        int ocg = (t2 >> 10) & 3, kc2 = (t2 >> 12) & 3, m = t2 >> 14;
        int oc = ocg * 32 + fr * 16 + (l & 15);
        int c  = kc2 * 32 + (l >> 4) * 8 + e;
        const float* W = (m == 0) ? qw : (m == 1) ? kw_ : vw;
        float v = W[oc * 128 + c];
        unsigned short hi = f2bf(v);
        wqh[t2] = hi; wql[t2] = f2bf(v - bf2f(hi));
    }
}

#define MFMA3(ACC, AH, AL, BH, BL) \
    ACC = __builtin_amdgcn_mfma_f32_16x16x32_bf16(AL, BH, ACC, 0, 0, 0); \
    ACC = __builtin_amdgcn_mfma_f32_16x16x32_bf16(AH, BL, ACC, 0, 0, 0); \
    ACC = __builtin_amdgcn_mfma_f32_16x16x32_bf16(AH, BH, ACC, 0, 0, 0);

// --- fused MFMA (bf16x3): 3x3 conv + GELU + QKV; 512 thr, 8 waves ---
// block = 4x8 positions x 128 oc; wave = 16 pos x 32 oc (posg = wid>>2, ocg = wid&3)
__global__ __launch_bounds__(512) void convqkv_kernel(
    const unsigned short* __restrict__ xh, const unsigned short* __restrict__ xl,
    const unsigned short* __restrict__ wch, const unsigned short* __restrict__ wcl,
    const float* __restrict__ cb,
    const unsigned short* __restrict__ wqh, const unsigned short* __restrict__ wql,
    const float* __restrict__ qbias, const float* __restrict__ kbias,
    const float* __restrict__ vbias,
    float* __restrict__ qo, float* __restrict__ ko, float* __restrict__ vo)
{
    __shared__ __align__(16) short ph_s[3840];   // [6r][10c][64ch] swizzled, hi
    __shared__ __align__(16) short pl_s[3840];   // lo
    __shared__ __align__(16) short fh_s[4096];   // [32 pos][128 c] swizzled, hi
    __shared__ __align__(16) short fl_s[4096];   // lo
    int bid = blockIdx.x;
    int swz = (bid & 7) * 72 + (bid >> 3);   // 576 = 8*72, bijective
    int b = swz / 288, rem = swz - b * 288;
    int ty = rem / 12, tx = rem - ty * 12;
    int y0 = ty * 4, x0 = tx * 8;
    int tid = threadIdx.x;

    // stage 6x10x64 bf16 patch (hi+lo), 16B granules, XOR-swizzle by (col&7)
    if (tid < 480) {
        int g = tid;
        int row = g / 80, r2 = g - row * 80;
        int col = r2 >> 3, gc = r2 & 7;
        size_t srcoff = ((size_t)(b * 98 + y0 + row) * 98 + x0 + col) * 64 + gc * 8;
        int dst = ((row * 10 + col) << 6) + ((gc ^ (col & 7)) << 3);
        *(short8*)&ph_s[dst] = *(const short8*)(xh + srcoff);
        *(short8*)&pl_s[dst] = *(const short8*)(xl + srcoff);
    }
    __syncthreads();

    int wid = tid >> 6, l = tid & 63;
    int posg = wid >> 2, ocg = wid & 3;
    int l15 = l & 15, l4 = l >> 4;
    int oc0 = ocg * 32;
    int p0 = posg * 16 + l15;
    int r0 = p0 >> 3, xc = p0 & 7;

    f32x4 c00 = {0.f,0.f,0.f,0.f}, c01 = {0.f,0.f,0.f,0.f};

    #pragma unroll 3
    for (int s = 0; s < 9; ++s) {
        int dy = s / 3, dx = s - dy * 3;
        int colA = xc + dx, cswz = (colA & 7) << 3;
        #pragma unroll
        for (int ch = 0; ch < 2; ++ch) {
            int gr = (ch * 4 + l4) << 3;
            int ai = (((r0 + dy) * 10 + colA) << 6) + (gr ^ cswz);
            short8 ah = *(const short8*)&ph_s[ai];
            short8 al = *(const short8*)&pl_s[ai];
            int s2 = s * 2 + ch;
            int wb = ((s2 * 4 + ocg) * 2) * 512 + l * 8;
            short8 b0h = *(const short8*)(wch + wb);
            short8 b0l = *(const short8*)(wcl + wb);
            short8 b1h = *(const short8*)(wch + wb + 512);
            short8 b1l = *(const short8*)(wcl + wb + 512);
            MFMA3(c00, ah, al, b0h, b0l)
            MFMA3(c01, ah, al, b1h, b1l)
        }
    }

    // bias + exact GELU -> hi/lo bf16 -> swizzled f LDS
    float bias0 = cb[oc0 + l15], bias1 = cb[oc0 + 16 + l15];
    #pragma unroll
    for (int nf = 0; nf < 2; ++nf) {
        f32x4 a = nf == 0 ? c00 : c01;
        float bs = nf == 0 ? bias0 : bias1;
        int oc = oc0 + nf * 16 + l15;
        #pragma unroll
        for (int rr = 0; rr < 4; ++rr) {
            int p = posg * 16 + l4 * 4 + rr;
            float v = a[rr] + bs;
            float g = 0.5f * v * (1.f + erff(v * 0.70710678118654752f));
            unsigned short hi = f2bf(g);
            unsigned short lo = f2bf(g - bf2f(hi));
            int di = p * 128 + ((((oc >> 3) ^ (p & 7)) << 3) | (oc & 7));
            fh_s[di] = (short)hi;
            fl_s[di] = (short)lo;
        }
    }
    __syncthreads();

    // ---- QKV GEMM: A = f (16 pos of this posg), B = repacked wq ----
    short8 aqh[4], aql[4];
    #pragma unroll
    for (int kc2 = 0; kc2 < 4; ++kc2) {
        int gr2 = (kc2 * 4 + l4) << 3;
        int i0 = p0 * 128 + (gr2 ^ ((p0 & 7) << 3));
        aqh[kc2] = *(const short8*)&fh_s[i0];
        aql[kc2] = *(const short8*)&fl_s[i0];
    }

    #pragma unroll 1
    for (int m = 0; m < 3; ++m) {
        const float* Bi = (m == 0) ? qbias : (m == 1) ? kbias : vbias;
        float* Om = (m == 0) ? qo : (m == 1) ? ko : vo;
        f32x4 d0 = {0.f,0.f,0.f,0.f}, d1 = {0.f,0.f,0.f,0.f};
        #pragma unroll
        for (int kc2 = 0; kc2 < 4; ++kc2) {
            int wb = (((m * 4 + kc2) * 4 + ocg) * 2) * 512 + l * 8;
            short8 b0h = *(const short8*)(wqh + wb);
            short8 b0l = *(const short8*)(wql + wb);
            short8 b1h = *(const short8*)(wqh + wb + 512);
            short8 b1l = *(const short8*)(wql + wb + 512);
            MFMA3(d0, aqh[kc2], aql[kc2], b0h, b0l)
            MFMA3(d1, aqh[kc2], aql[kc2], b1h, b1l)
        }
        float bm0 = Bi[oc0 + l15], bm1 = Bi[oc0 + 16 + l15];
        #pragma unroll
        for (int nf = 0; nf < 2; ++nf) {
            f32x4 a = nf == 0 ? d0 : d1;
            float bs = nf == 0 ? bm0 : bm1;
            int oc = oc0 + nf * 16 + l15;
            #pragma unroll
            for (int rr = 0; rr < 4; ++rr) {
                int p = posg * 16 + l4 * 4 + rr;
                int yy = y0 + (p >> 3), xx = x0 + (p & 7);
                Om[((size_t)(b * HW + yy * Ww + xx)) * CMID + oc] = a[rr] + bs;
            }
        }
    }
}

// ---- 7x7 NAT: one wave per 2x2 query group; lane = union-window row ----
__global__ __launch_bounds__(256) void nat_kernel(const float* __restrict__ q,
    const float* __restrict__ k, const float* __restrict__ v,
    float* __restrict__ out)
{
    int bid = blockIdx.x;
    int swz = (bid & 7) * 144 + (bid >> 3);  // 1152 = 8*144, bijective
    int tid = threadIdx.x;
    int wid = tid >> 6, lane = tid & 63;
    int g = __builtin_amdgcn_readfirstlane(swz * 4 + wid);  // 0..4607
    int b = g / 2304, rem = g - b * 2304;
    int ti = rem / 48, tj = rem - ti * 48;
    int i0 = ti * 2, j0 = tj * 2;

    int si0 = i0 - 3; si0 = si0 < 0 ? 0 : (si0 > 89 ? 89 : si0);
    int si1 = i0 - 2; si1 = si1 < 0 ? 0 : (si1 > 89 ? 89 : si1);
    int sj0 = j0 - 3; sj0 = sj0 < 0 ? 0 : (sj0 > 89 ? 89 : sj0);
    int sj1 = j0 - 2; sj1 = sj1 < 0 ? 0 : (sj1 > 89 ? 89 : sj1);
    int ui = si0 > 88 ? 88 : si0;
    int uj = sj0 > 88 ? 88 : sj0;
    int oi0 = si0 - ui, oi1 = si1 - ui, oj0 = sj0 - uj, oj1 = sj1 - uj;
    int base2 = b * HW + ui * Ww + uj;

    int wr = lane >> 3, wc = lane & 7;

    const float4* kp  = (const float4*)(k + (size_t)(base2 + wr * Ww + wc) * CMID);
    const float4* qp0 = (const float4*)(q + (size_t)(b * HW + i0 * Ww + j0) * CMID);
    const float4* qp2 = (const float4*)(q + (size_t)(b * HW + (i0 + 1) * Ww + j0) * CMID);
    float a0 = 0.f, a1 = 0.f, a2 = 0.f, a3 = 0.f;
    #pragma unroll
    for (int c = 0; c < 32; ++c) {
        float4 kv = kp[c];
        float4 q0 = qp0[c], q1 = qp0[c + 32], q2 = qp2[c], q3 = qp2[c + 32];
        a0 = fmaf(q0.x, kv.x, a0); a0 = fmaf(q0.y, kv.y, a0);
        a0 = fmaf(q0.z, kv.z, a0); a0 = fmaf(q0.w, kv.w, a0);
        a1 = fmaf(q1.x, kv.x, a1); a1 = fmaf(q1.y, kv.y, a1);
        a1 = fmaf(q1.z, kv.z, a1); a1 = fmaf(q1.w, kv.w, a1);
        a2 = fmaf(q2.x, kv.x, a2); a2 = fmaf(q2.y, kv.y, a2);
        a2 = fmaf(q2.z, kv.z, a2); a2 = fmaf(q2.w, kv.w, a2);
        a3 = fmaf(q3.x, kv.x, a3); a3 = fmaf(q3.y, kv.y, a3);
        a3 = fmaf(q3.z, kv.z, a3); a3 = fmaf(q3.w, kv.w, a3);
    }

    float l0 = ((unsigned)(wr - oi0) <= 6u && (unsigned)(wc - oj0) <= 6u) ? a0 * NAT_SCALE : -INFINITY;
    float l1 = ((unsigned)(wr - oi0) <= 6u && (unsigned)(wc - oj1) <= 6u) ? a1 * NAT_SCALE : -INFINITY;
    float l2 = ((unsigned)(wr - oi1) <= 6u && (unsigned)(wc - oj0) <= 6u) ? a2 * NAT_SCALE : -INFINITY;
    float l3 = ((unsigned)(wr - oi1) <= 6u && (unsigned)(wc - oj1) <= 6u) ? a3 * NAT_SCALE : -INFINITY;
    float m0 = l0, m1 = l1, m2 = l2, m3 = l3;
    #pragma unroll
    for (int d = 1; d < 64; d <<= 1) {
        m0 = fmaxf(m0, __shfl_xor(m0, d)); m1 = fmaxf(m1, __shfl_xor(m1, d));
        m2 = fmaxf(m2, __shfl_xor(m2, d)); m3 = fmaxf(m3, __shfl_xor(m3, d));
    }
    float e0 = __expf(l0 - m0), e1 = __expf(l1 - m1);
    float e2 = __expf(l2 - m2), e3 = __expf(l3 - m3);
    float s0 = e0, s1 = e1, s2 = e2, s3 = e3;
    #pragma unroll
    for (int d = 1; d < 64; d <<= 1) {
        s0 += __shfl_xor(s0, d); s1 += __shfl_xor(s1, d);
        s2 += __shfl_xor(s2, d); s3 += __shfl_xor(s3, d);
    }
    float w0 = e0 / s0, w1 = e1 / s1, w2 = e2 / s2, w3 = e3 / s3;

    const float2* vbase = (const float2*)(v + (size_t)base2 * CMID);
    float2 o0 = {0.f, 0.f}, o1 = {0.f, 0.f}, o2 = {0.f, 0.f}, o3 = {0.f, 0.f};
    #pragma unroll
    for (int w = 0; w < 64; ++w) {
        int off = ((w >> 3) * Ww + (w & 7)) * 64;
        float2 vv = vbase[off + lane];
        float b0 = __shfl(w0, w), b1 = __shfl(w1, w);
        float b2 = __shfl(w2, w), b3 = __shfl(w3, w);
        o0.x = fmaf(b0, vv.x, o0.x); o0.y = fmaf(b0, vv.y, o0.y);
        o1.x = fmaf(b1, vv.x, o1.x); o1.y = fmaf(b1, vv.y, o1.y);
        o2.x = fmaf(b2, vv.x, o2.x); o2.y = fmaf(b2, vv.y, o2.y);
        o3.x = fmaf(b3, vv.x, o3.x); o3.y = fmaf(b3, vv.y, o3.y);
    }

    size_t ob = ((size_t)(b * CMID + 2 * lane)) * HW + i0 * Ww + j0;
    float2 r0 = {o0.x, o1.x}, r1 = {o0.y, o1.y};
    float2 r2 = {o2.x, o3.x}, r3 = {o2.y, o3.y};
    *(float2*)(out + ob)           = r0;
    *(float2*)(out + ob + HW)      = r1;
    *(float2*)(out + ob + Ww)      = r2;
    *(float2*)(out + ob + HW + Ww) = r3;
}

extern "C" void kernel_launch(void* const* d_in, const int* in_sizes, int n_in,
                              void* d_out, int out_size, void* d_ws, size_t ws_size,
                              hipStream_t stream) {
    const float* x      = (const float*)d_in[0];
    const float* gn_w   = (const float*)d_in[1];
    const float* gn_b   = (const float*)d_in[2];
    const float* conv_w = (const float*)d_in[3];
    const float* conv_b = (const float*)d_in[4];
    const float* q_w    = (const float*)d_in[5];
    const float* q_b    = (const float*)d_in[6];
    const float* k_w    = (const float*)d_in[7];
    const float* k_b    = (const float*)d_in[8];
    const float* v_w    = (const float*)d_in[9];
    const float* v_b    = (const float*)d_in[10];

    const size_t XNP = (size_t)2 * 98 * 98 * 64;      // 1,229,312 per plane
    float* ws    = (float*)d_ws;
    float2* partials = (float2*)ws;                    // 512 float2
    float* qb_   = ws + 1024;                          // 3 x 2,359,296 fp32 NHWC
    float* kb_   = qb_ + (size_t)2 * CMID * HW;
    float* vb_   = kb_ + (size_t)2 * CMID * HW;
    unsigned short* xnh = (unsigned short*)(vb_ + (size_t)2 * CMID * HW);
    unsigned short* xnl = xnh + XNP;
    unsigned short* wch = xnl + XNP;                   // 73,728 each
    unsigned short* wcl = wch + 73728;
    unsigned short* wqh = wcl + 73728;                 // 49,152 each
    unsigned short* wql = wqh + 49152;

    gn_partial_kernel<<<512, 256, 0, stream>>>(x, partials);
    hipMemsetAsync(xnh, 0, XNP * 2 * sizeof(unsigned short), stream);
    repack_kernel<<<480, 256, 0, stream>>>(conv_w, q_w, k_w, v_w,
                                           wch, wcl, wqh, wql);
    gnapply_kernel<<<768, 256, 0, stream>>>(x, partials, gn_w, gn_b, xnh, xnl);
    convqkv_kernel<<<576, 512, 0, stream>>>(xnh, xnl, wch, wcl, conv_b,
                                            wqh, wql, q_b, k_b, v_b,
                                            qb_, kb_, vb_);
    nat_kernel<<<1152, 256, 0, stream>>>(qb_, kb_, vb_, (float*)d_out);
}

// Round 10
// 85.764 us; speedup vs baseline: 7.5694x; 1.0032x over previous
//
#include <hip/hip_runtime.h>
#include <math.h>

#define Hh 96
#define Ww 96
#define HW 9216
#define CIN 64
#define CMID 128
#define NAT_SCALE 11.313708498984761f   // sqrt(128), multiplies logits

typedef __attribute__((ext_vector_type(4))) float f32x4;
typedef __attribute__((ext_vector_type(8))) short short8;

__device__ __forceinline__ unsigned short f2bf(float x) {
    union { float f; unsigned u; } v; v.f = x;
    unsigned r = v.u + 0x7FFF + ((v.u >> 16) & 1);     // RNE
    return (unsigned short)(r >> 16);
}
__device__ __forceinline__ float bf2f(unsigned short h) {
    union { unsigned u; float f; } v; v.u = (unsigned)h << 16;
    return v.f;
}

// ---------- GN stats stage 1: 512 blocks, partial sums ----------
__global__ __launch_bounds__(256) void gn_partial_kernel(const float* __restrict__ x,
    float2* __restrict__ partials)
{
    int blk = blockIdx.x;                    // (b*16+g)*16 + sub
    int tid = threadIdx.x;
    size_t base = (size_t)(blk >> 4) * 36864 + (size_t)(blk & 15) * 2304;
    float s = 0.f, s2 = 0.f;
    #pragma unroll
    for (int i = 0; i < 9; ++i) {
        float v = x[base + i * 256 + tid];
        s += v; s2 += v * v;
    }
    #pragma unroll
    for (int d = 1; d < 64; d <<= 1) {
        s  += __shfl_xor(s, d);
        s2 += __shfl_xor(s2, d);
    }
    __shared__ float as[4], as2[4];
    int wid = tid >> 6, lane = tid & 63;
    if (lane == 0) { as[wid] = s; as2[wid] = s2; }
    __syncthreads();
    if (tid == 0) {
        float2 r = { as[0]+as[1]+as[2]+as[3], as2[0]+as2[1]+as2[2]+as2[3] };
        partials[blk] = r;
    }
}

// ---- zero the pad frame of xn_pad hi/lo (replaces 4.9MB runtime memset) ----
__global__ __launch_bounds__(256) void border_kernel(
    unsigned short* __restrict__ xh, unsigned short* __restrict__ xl)
{
    int t = blockIdx.x * 256 + threadIdx.x;  // 2b x 388 pos x 8 granules = 6208
    if (t >= 6208) return;
    int b = t / 3104, r = t - b * 3104;
    int pos = r >> 3, gc = r & 7;
    int y, xx;
    if (pos < 98)      { y = 0;          xx = pos; }
    else if (pos < 196){ y = 97;         xx = pos - 98; }
    else if (pos < 292){ y = pos - 195;  xx = 0; }    // rows 1..96
    else               { y = pos - 291;  xx = 97; }   // rows 1..96
    size_t off = ((size_t)(b * 98 + y) * 98 + xx) * 64 + gc * 8;
    short8 z = {0,0,0,0,0,0,0,0};
    *(short8*)(xh + off) = z;
    *(short8*)(xl + off) = z;
}

// ---- GN-apply -> padded NHWC bf16 hi/lo planes [b][98][98][64] ----
// grid = 2b x 96y x 4 quarters; folds the stats finalize (reads partials)
__global__ __launch_bounds__(256) void gnapply_kernel(const float* __restrict__ x,
    const float2* __restrict__ partials,
    const float* __restrict__ gw, const float* __restrict__ gb,
    unsigned short* __restrict__ xh, unsigned short* __restrict__ xl)
{
    __shared__ float tin[64 * 25];           // [c][24+1]
    __shared__ float sgld[32];               // 16 groups x {mean, rstd}
    int blk = blockIdx.x;                    // b*384 + y*4 + q
    int b = blk / 384, r1 = blk - b * 384;
    int y = r1 >> 2, q = r1 & 3;
    int tid = threadIdx.x;

    if (tid < 256) {                         // finalize this batch's 16 groups
        float2 pv = partials[b * 256 + tid];
        float s = pv.x, s2 = pv.y;
        #pragma unroll
        for (int d = 1; d < 16; d <<= 1) {
            s  += __shfl_xor(s, d);
            s2 += __shfl_xor(s2, d);
        }
        if ((tid & 15) == 0) {
            const float invN = 1.f / 36864.f;
            float mean = s * invN;
            float var  = s2 * invN - mean * mean;
            sgld[(tid >> 4) * 2]     = mean;
            sgld[(tid >> 4) * 2 + 1] = rsqrtf(var + 1e-5f);
        }
    }
    #pragma unroll
    for (int i = 0; i < 6; ++i) {            // stage raw 64c x 24x
        int idx = i * 256 + tid;             // 1536
        int c = idx / 24, xx = idx - c * 24;
        tin[c * 25 + xx] = x[((size_t)(b * CIN + c)) * HW + y * Ww + q * 24 + xx];
    }
    __syncthreads();
    #pragma unroll
    for (int i = 0; i < 6; ++i) {
        int idx = i * 256 + tid;
        int xx = idx >> 6, c = idx & 63;
        float v = tin[c * 25 + xx];
        float val = (v - sgld[(c >> 2) * 2]) * sgld[(c >> 2) * 2 + 1] * gw[c] + gb[c];
        unsigned short hi = f2bf(val);
        unsigned short lo = f2bf(val - bf2f(hi));
        size_t dst = ((size_t)(b * 98 + y + 1) * 98 + q * 24 + xx + 1) * 64 + c;
        xh[dst] = hi; xl[dst] = lo;
    }
}

// ---- weight repack (conv + qkv), lane-exact coalesced layout ----
// conv: [s2(18)][ocg(4)][fr(2)][lane(64)][e(8)]  src cw[oc][c*9+s]
// qkv : [m(3)][kc2(4)][ocg(4)][fr(2)][lane(64)][e(8)]  src W[oc][c]
__global__ __launch_bounds__(256) void repack_kernel(const float* __restrict__ cw,
    const float* __restrict__ qw, const float* __restrict__ kw_,
    const float* __restrict__ vw,
    unsigned short* __restrict__ wch, unsigned short* __restrict__ wcl,
    unsigned short* __restrict__ wqh, unsigned short* __restrict__ wql)
{
    int t = blockIdx.x * 256 + threadIdx.x;  // 122880 total
    if (t < 73728) {
        int e = t & 7, l = (t >> 3) & 63, fr = (t >> 9) & 1;
        int ocg = (t >> 10) & 3, s2 = t >> 12;      // 0..17
        int s = s2 >> 1, ch = s2 & 1;
        int oc = ocg * 32 + fr * 16 + (l & 15);
        int c  = ch * 32 + (l >> 4) * 8 + e;
        float v = cw[oc * 576 + c * 9 + s];
        unsigned short hi = f2bf(v);
        wch[t] = hi; wcl[t] = f2bf(v - bf2f(hi));
    } else {
        int t2 = t - 73728;                  // < 49152
        int e = t2 & 7, l = (t2 >> 3) & 63, fr = (t2 >> 9) & 1;
        int ocg = (t2 >> 10) & 3, kc2 = (t2 >> 12) & 3, m = t2 >> 14;
        int oc = ocg * 32 + fr * 16 + (l & 15);
        int c  = kc2 * 32 + (l >> 4) * 8 + e;
        const float* W = (m == 0) ? qw : (m == 1) ? kw_ : vw;
        float v = W[oc * 128 + c];
        unsigned short hi = f2bf(v);
        wqh[t2] = hi; wql[t2] = f2bf(v - bf2f(hi));
    }
}

#define MFMA3(ACC, AH, AL, BH, BL) \
    ACC = __builtin_amdgcn_mfma_f32_16x16x32_bf16(AL, BH, ACC, 0, 0, 0); \
    ACC = __builtin_amdgcn_mfma_f32_16x16x32_bf16(AH, BL, ACC, 0, 0, 0); \
    ACC = __builtin_amdgcn_mfma_f32_16x16x32_bf16(AH, BH, ACC, 0, 0, 0);

// --- fused MFMA (bf16x3): 3x3 conv + GELU + QKV; 512 thr, 8 waves ---
// block = 4x8 positions x 128 oc; wave = 16 pos x 32 oc (posg = wid>>2, ocg = wid&3)
__global__ __launch_bounds__(512) void convqkv_kernel(
    const unsigned short* __restrict__ xh, const unsigned short* __restrict__ xl,
    const unsigned short* __restrict__ wch, const unsigned short* __restrict__ wcl,
    const float* __restrict__ cb,
    const unsigned short* __restrict__ wqh, const unsigned short* __restrict__ wql,
    const float* __restrict__ qbias, const float* __restrict__ kbias,
    const float* __restrict__ vbias,
    float* __restrict__ qo, float* __restrict__ ko, float* __restrict__ vo)
{
    __shared__ __align__(16) short ph_s[3840];   // [6r][10c][64ch] swizzled, hi
    __shared__ __align__(16) short pl_s[3840];   // lo
    __shared__ __align__(16) short fh_s[4096];   // [32 pos][128 c] swizzled, hi
    __shared__ __align__(16) short fl_s[4096];   // lo
    int bid = blockIdx.x;
    int swz = (bid & 7) * 72 + (bid >> 3);   // 576 = 8*72, bijective
    int b = swz / 288, rem = swz - b * 288;
    int ty = rem / 12, tx = rem - ty * 12;
    int y0 = ty * 4, x0 = tx * 8;
    int tid = threadIdx.x;

    // stage 6x10x64 bf16 patch (hi+lo), 16B granules, XOR-swizzle by (col&7)
    if (tid < 480) {
        int g = tid;
        int row = g / 80, r2 = g - row * 80;
        int col = r2 >> 3, gc = r2 & 7;
        size_t srcoff = ((size_t)(b * 98 + y0 + row) * 98 + x0 + col) * 64 + gc * 8;
        int dst = ((row * 10 + col) << 6) + ((gc ^ (col & 7)) << 3);
        *(short8*)&ph_s[dst] = *(const short8*)(xh + srcoff);
        *(short8*)&pl_s[dst] = *(const short8*)(xl + srcoff);
    }
    __syncthreads();

    int wid = tid >> 6, l = tid & 63;
    int posg = wid >> 2, ocg = wid & 3;
    int l15 = l & 15, l4 = l >> 4;
    int oc0 = ocg * 32;
    int p0 = posg * 16 + l15;
    int r0 = p0 >> 3, xc = p0 & 7;

    f32x4 c00 = {0.f,0.f,0.f,0.f}, c01 = {0.f,0.f,0.f,0.f};

    #pragma unroll 3
    for (int s = 0; s < 9; ++s) {
        int dy = s / 3, dx = s - dy * 3;
        int colA = xc + dx, cswz = (colA & 7) << 3;
        #pragma unroll
        for (int ch = 0; ch < 2; ++ch) {
            int gr = (ch * 4 + l4) << 3;
            int ai = (((r0 + dy) * 10 + colA) << 6) + (gr ^ cswz);
            short8 ah = *(const short8*)&ph_s[ai];
            short8 al = *(const short8*)&pl_s[ai];
            int s2 = s * 2 + ch;
            int wb = ((s2 * 4 + ocg) * 2) * 512 + l * 8;
            short8 b0h = *(const short8*)(wch + wb);
            short8 b0l = *(const short8*)(wcl + wb);
            short8 b1h = *(const short8*)(wch + wb + 512);
            short8 b1l = *(const short8*)(wcl + wb + 512);
            MFMA3(c00, ah, al, b0h, b0l)
            MFMA3(c01, ah, al, b1h, b1l)
        }
    }

    // bias + exact GELU -> hi/lo bf16 -> swizzled f LDS
    float bias0 = cb[oc0 + l15], bias1 = cb[oc0 + 16 + l15];
    #pragma unroll
    for (int nf = 0; nf < 2; ++nf) {
        f32x4 a = nf == 0 ? c00 : c01;
        float bs = nf == 0 ? bias0 : bias1;
        int oc = oc0 + nf * 16 + l15;
        #pragma unroll
        for (int rr = 0; rr < 4; ++rr) {
            int p = posg * 16 + l4 * 4 + rr;
            float v = a[rr] + bs;
            float g = 0.5f * v * (1.f + erff(v * 0.70710678118654752f));
            unsigned short hi = f2bf(g);
            unsigned short lo = f2bf(g - bf2f(hi));
            int di = p * 128 + ((((oc >> 3) ^ (p & 7)) << 3) | (oc & 7));
            fh_s[di] = (short)hi;
            fl_s[di] = (short)lo;
        }
    }
    __syncthreads();

    // ---- QKV GEMM: A = f (16 pos of this posg), B = repacked wq ----
    short8 aqh[4], aql[4];
    #pragma unroll
    for (int kc2 = 0; kc2 < 4; ++kc2) {
        int gr2 = (kc2 * 4 + l4) << 3;
        int i0 = p0 * 128 + (gr2 ^ ((p0 & 7) << 3));
        aqh[kc2] = *(const short8*)&fh_s[i0];
        aql[kc2] = *(const short8*)&fl_s[i0];
    }

    #pragma unroll 1
    for (int m = 0; m < 3; ++m) {
        const float* Bi = (m == 0) ? qbias : (m == 1) ? kbias : vbias;
        float* Om = (m == 0) ? qo : (m == 1) ? ko : vo;
        f32x4 d0 = {0.f,0.f,0.f,0.f}, d1 = {0.f,0.f,0.f,0.f};
        #pragma unroll
        for (int kc2 = 0; kc2 < 4; ++kc2) {
            int wb = (((m * 4 + kc2) * 4 + ocg) * 2) * 512 + l * 8;
            short8 b0h = *(const short8*)(wqh + wb);
            short8 b0l = *(const short8*)(wql + wb);
            short8 b1h = *(const short8*)(wqh + wb + 512);
            short8 b1l = *(const short8*)(wql + wb + 512);
            MFMA3(d0, aqh[kc2], aql[kc2], b0h, b0l)
            MFMA3(d1, aqh[kc2], aql[kc2], b1h, b1l)
        }
        float bm0 = Bi[oc0 + l15], bm1 = Bi[oc0 + 16 + l15];
        #pragma unroll
        for (int nf = 0; nf < 2; ++nf) {
            f32x4 a = nf == 0 ? d0 : d1;
            float bs = nf == 0 ? bm0 : bm1;
            int oc = oc0 + nf * 16 + l15;
            #pragma unroll
            for (int rr = 0; rr < 4; ++rr) {
                int p = posg * 16 + l4 * 4 + rr;
                int yy = y0 + (p >> 3), xx = x0 + (p & 7);
                Om[((size_t)(b * HW + yy * Ww + xx)) * CMID + oc] = a[rr] + bs;
            }
        }
    }
}

// ---- 7x7 NAT: one wave per 2x2 query group; lane = union-window row ----
__global__ __launch_bounds__(256) void nat_kernel(const float* __restrict__ q,
    const float* __restrict__ k, const float* __restrict__ v,
    float* __restrict__ out)
{
    int bid = blockIdx.x;
    int swz = (bid & 7) * 144 + (bid >> 3);  // 1152 = 8*144, bijective
    int tid = threadIdx.x;
    int wid = tid >> 6, lane = tid & 63;
    int g = __builtin_amdgcn_readfirstlane(swz * 4 + wid);  // 0..4607
    int b = g / 2304, rem = g - b * 2304;
    int ti = rem / 48, tj = rem - ti * 48;
    int i0 = ti * 2, j0 = tj * 2;

    int si0 = i0 - 3; si0 = si0 < 0 ? 0 : (si0 > 89 ? 89 : si0);
    int si1 = i0 - 2; si1 = si1 < 0 ? 0 : (si1 > 89 ? 89 : si1);
    int sj0 = j0 - 3; sj0 = sj0 < 0 ? 0 : (sj0 > 89 ? 89 : sj0);
    int sj1 = j0 - 2; sj1 = sj1 < 0 ? 0 : (sj1 > 89 ? 89 : sj1);
    int ui = si0 > 88 ? 88 : si0;
    int uj = sj0 > 88 ? 88 : sj0;
    int oi0 = si0 - ui, oi1 = si1 - ui, oj0 = sj0 - uj, oj1 = sj1 - uj;
    int base2 = b * HW + ui * Ww + uj;

    int wr = lane >> 3, wc = lane & 7;

    const float4* kp  = (const float4*)(k + (size_t)(base2 + wr * Ww + wc) * CMID);
    const float4* qp0 = (const float4*)(q + (size_t)(b * HW + i0 * Ww + j0) * CMID);
    const float4* qp2 = (const float4*)(q + (size_t)(b * HW + (i0 + 1) * Ww + j0) * CMID);
    float a0 = 0.f, a1 = 0.f, a2 = 0.f, a3 = 0.f;
    #pragma unroll
    for (int c = 0; c < 32; ++c) {
        float4 kv = kp[c];
        float4 q0 = qp0[c], q1 = qp0[c + 32], q2 = qp2[c], q3 = qp2[c + 32];
        a0 = fmaf(q0.x, kv.x, a0); a0 = fmaf(q0.y, kv.y, a0);
        a0 = fmaf(q0.z, kv.z, a0); a0 = fmaf(q0.w, kv.w, a0);
        a1 = fmaf(q1.x, kv.x, a1); a1 = fmaf(q1.y, kv.y, a1);
        a1 = fmaf(q1.z, kv.z, a1); a1 = fmaf(q1.w, kv.w, a1);
        a2 = fmaf(q2.x, kv.x, a2); a2 = fmaf(q2.y, kv.y, a2);
        a2 = fmaf(q2.z, kv.z, a2); a2 = fmaf(q2.w, kv.w, a2);
        a3 = fmaf(q3.x, kv.x, a3); a3 = fmaf(q3.y, kv.y, a3);
        a3 = fmaf(q3.z, kv.z, a3); a3 = fmaf(q3.w, kv.w, a3);
    }

    float l0 = ((unsigned)(wr - oi0) <= 6u && (unsigned)(wc - oj0) <= 6u) ? a0 * NAT_SCALE : -INFINITY;
    float l1 = ((unsigned)(wr - oi0) <= 6u && (unsigned)(wc - oj1) <= 6u) ? a1 * NAT_SCALE : -INFINITY;
    float l2 = ((unsigned)(wr - oi1) <= 6u && (unsigned)(wc - oj0) <= 6u) ? a2 * NAT_SCALE : -INFINITY;
    float l3 = ((unsigned)(wr - oi1) <= 6u && (unsigned)(wc - oj1) <= 6u) ? a3 * NAT_SCALE : -INFINITY;
    float m0 = l0, m1 = l1, m2 = l2, m3 = l3;
    #pragma unroll
    for (int d = 1; d < 64; d <<= 1) {
        m0 = fmaxf(m0, __shfl_xor(m0, d)); m1 = fmaxf(m1, __shfl_xor(m1, d));
        m2 = fmaxf(m2, __shfl_xor(m2, d)); m3 = fmaxf(m3, __shfl_xor(m3, d));
    }
    float e0 = __expf(l0 - m0), e1 = __expf(l1 - m1);
    float e2 = __expf(l2 - m2), e3 = __expf(l3 - m3);
    float s0 = e0, s1 = e1, s2 = e2, s3 = e3;
    #pragma unroll
    for (int d = 1; d < 64; d <<= 1) {
        s0 += __shfl_xor(s0, d); s1 += __shfl_xor(s1, d);
        s2 += __shfl_xor(s2, d); s3 += __shfl_xor(s3, d);
    }
    float w0 = e0 / s0, w1 = e1 / s1, w2 = e2 / s2, w3 = e3 / s3;

    const float2* vbase = (const float2*)(v + (size_t)base2 * CMID);
    float2 o0 = {0.f, 0.f}, o1 = {0.f, 0.f}, o2 = {0.f, 0.f}, o3 = {0.f, 0.f};
    #pragma unroll
    for (int w = 0; w < 64; ++w) {
        int off = ((w >> 3) * Ww + (w & 7)) * 64;
        float2 vv = vbase[off + lane];
        float b0 = __shfl(w0, w), b1 = __shfl(w1, w);
        float b2 = __shfl(w2, w), b3 = __shfl(w3, w);
        o0.x = fmaf(b0, vv.x, o0.x); o0.y = fmaf(b0, vv.y, o0.y);
        o1.x = fmaf(b1, vv.x, o1.x); o1.y = fmaf(b1, vv.y, o1.y);
        o2.x = fmaf(b2, vv.x, o2.x); o2.y = fmaf(b2, vv.y, o2.y);
        o3.x = fmaf(b3, vv.x, o3.x); o3.y = fmaf(b3, vv.y, o3.y);
    }

    size_t ob = ((size_t)(b * CMID + 2 * lane)) * HW + i0 * Ww + j0;
    float2 r0 = {o0.x, o1.x}, r1 = {o0.y, o1.y};
    float2 r2 = {o2.x, o3.x}, r3 = {o2.y, o3.y};
    *(float2*)(out + ob)           = r0;
    *(float2*)(out + ob + HW)      = r1;
    *(float2*)(out + ob + Ww)      = r2;
    *(float2*)(out + ob + HW + Ww) = r3;
}

extern "C" void kernel_launch(void* const* d_in, const int* in_sizes, int n_in,
                              void* d_out, int out_size, void* d_ws, size_t ws_size,
                              hipStream_t stream) {
    const float* x      = (const float*)d_in[0];
    const float* gn_w   = (const float*)d_in[1];
    const float* gn_b   = (const float*)d_in[2];
    const float* conv_w = (const float*)d_in[3];
    const float* conv_b = (const float*)d_in[4];
    const float* q_w    = (const float*)d_in[5];
    const float* q_b    = (const float*)d_in[6];
    const float* k_w    = (const float*)d_in[7];
    const float* k_b    = (const float*)d_in[8];
    const float* v_w    = (const float*)d_in[9];
    const float* v_b    = (const float*)d_in[10];

    const size_t XNP = (size_t)2 * 98 * 98 * 64;      // 1,229,312 per plane
    float* ws    = (float*)d_ws;
    float2* partials = (float2*)ws;                    // 512 float2
    float* qb_   = ws + 1024;                          // 3 x 2,359,296 fp32 NHWC
    float* kb_   = qb_ + (size_t)2 * CMID * HW;
    float* vb_   = kb_ + (size_t)2 * CMID * HW;
    unsigned short* xnh = (unsigned short*)(vb_ + (size_t)2 * CMID * HW);
    unsigned short* xnl = xnh + XNP;
    unsigned short* wch = xnl + XNP;                   // 73,728 each
    unsigned short* wcl = wch + 73728;
    unsigned short* wqh = wcl + 73728;                 // 49,152 each
    unsigned short* wql = wqh + 49152;

    gn_partial_kernel<<<512, 256, 0, stream>>>(x, partials);
    border_kernel<<<25, 256, 0, stream>>>(xnh, xnl);
    repack_kernel<<<480, 256, 0, stream>>>(conv_w, q_w, k_w, v_w,
                                           wch, wcl, wqh, wql);
    gnapply_kernel<<<768, 256, 0, stream>>>(x, partials, gn_w, gn_b, xnh, xnl);
    convqkv_kernel<<<576, 512, 0, stream>>>(xnh, xnl, wch, wcl, conv_b,
                                            wqh, wql, q_b, k_b, v_b,
                                            qb_, kb_, vb_);
    nat_kernel<<<1152, 256, 0, stream>>>(qb_, kb_, vb_, (float*)d_out);
}

// Round 11
// 75.808 us; speedup vs baseline: 8.5635x; 1.1313x over previous
//
#include <hip/hip_runtime.h>
#include <math.h>

#define Hh 96
#define Ww 96
#define HW 9216
#define CIN 64
#define CMID 128
#define NAT_SCALE 11.313708498984761f   // sqrt(128), multiplies logits

typedef __attribute__((ext_vector_type(4))) float f32x4;
typedef __attribute__((ext_vector_type(8))) short short8;

__device__ __forceinline__ unsigned short f2bf(float x) {
    union { float f; unsigned u; } v; v.f = x;
    unsigned r = v.u + 0x7FFF + ((v.u >> 16) & 1);     // RNE
    return (unsigned short)(r >> 16);
}
__device__ __forceinline__ float bf2f(unsigned short h) {
    union { unsigned u; float f; } v; v.u = (unsigned)h << 16;
    return v.f;
}

// ---- prep: gn partial sums (512 blk) + weight repack (480 blk) + border (25) ----
__global__ __launch_bounds__(256) void prep_kernel(const float* __restrict__ x,
    float2* __restrict__ partials,
    const float* __restrict__ cw, const float* __restrict__ qw,
    const float* __restrict__ kw_, const float* __restrict__ vw,
    unsigned short* __restrict__ wch, unsigned short* __restrict__ wcl,
    unsigned short* __restrict__ wqh, unsigned short* __restrict__ wql,
    unsigned short* __restrict__ xh, unsigned short* __restrict__ xl)
{
    int bid = blockIdx.x, tid = threadIdx.x;
    if (bid < 512) {                         // GN partial sums
        size_t base = (size_t)(bid >> 4) * 36864 + (size_t)(bid & 15) * 2304;
        float s = 0.f, s2 = 0.f;
        #pragma unroll
        for (int i = 0; i < 9; ++i) {
            float v = x[base + i * 256 + tid];
            s += v; s2 += v * v;
        }
        #pragma unroll
        for (int d = 1; d < 64; d <<= 1) {
            s  += __shfl_xor(s, d);
            s2 += __shfl_xor(s2, d);
        }
        __shared__ float as[4], as2[4];
        int wid = tid >> 6, lane = tid & 63;
        if (lane == 0) { as[wid] = s; as2[wid] = s2; }
        __syncthreads();
        if (tid == 0) {
            float2 r = { as[0]+as[1]+as[2]+as[3], as2[0]+as2[1]+as2[2]+as2[3] };
            partials[bid] = r;
        }
    } else if (bid < 992) {                  // weight repack
        int t = (bid - 512) * 256 + tid;     // < 122880
        if (t < 73728) {
            int e = t & 7, l = (t >> 3) & 63, fr = (t >> 9) & 1;
            int ocg = (t >> 10) & 3, s2 = t >> 12;      // 0..17
            int s = s2 >> 1, ch = s2 & 1;
            int oc = ocg * 32 + fr * 16 + (l & 15);
            int c  = ch * 32 + (l >> 4) * 8 + e;
            float v = cw[oc * 576 + c * 9 + s];
            unsigned short hi = f2bf(v);
            wch[t] = hi; wcl[t] = f2bf(v - bf2f(hi));
        } else {
            int t2 = t - 73728;              // < 49152
            int e = t2 & 7, l = (t2 >> 3) & 63, fr = (t2 >> 9) & 1;
            int ocg = (t2 >> 10) & 3, kc2 = (t2 >> 12) & 3, m = t2 >> 14;
            int oc = ocg * 32 + fr * 16 + (l & 15);
            int c  = kc2 * 32 + (l >> 4) * 8 + e;
            const float* W = (m == 0) ? qw : (m == 1) ? kw_ : vw;
            float v = W[oc * 128 + c];
            unsigned short hi = f2bf(v);
            wqh[t2] = hi; wql[t2] = f2bf(v - bf2f(hi));
        }
    } else {                                 // zero pad frame of xn_pad
        int t = (bid - 992) * 256 + tid;     // < 6400, need 6208
        if (t < 6208) {
            int b = t / 3104, r = t - b * 3104;
            int pos = r >> 3, gc = r & 7;
            int y, xx;
            if (pos < 98)      { y = 0;          xx = pos; }
            else if (pos < 196){ y = 97;         xx = pos - 98; }
            else if (pos < 292){ y = pos - 195;  xx = 0; }
            else               { y = pos - 291;  xx = 97; }
            size_t off = ((size_t)(b * 98 + y) * 98 + xx) * 64 + gc * 8;
            short8 z = {0,0,0,0,0,0,0,0};
            *(short8*)(xh + off) = z;
            *(short8*)(xl + off) = z;
        }
    }
}

// ---- GN-apply -> padded NHWC bf16 hi/lo planes [b][98][98][64] ----
__global__ __launch_bounds__(256) void gnapply_kernel(const float* __restrict__ x,
    const float2* __restrict__ partials,
    const float* __restrict__ gw, const float* __restrict__ gb,
    unsigned short* __restrict__ xh, unsigned short* __restrict__ xl)
{
    __shared__ float tin[64 * 25];           // [c][24+1]
    __shared__ float sgld[32];               // 16 groups x {mean, rstd}
    int blk = blockIdx.x;                    // b*384 + y*4 + q
    int b = blk / 384, r1 = blk - b * 384;
    int y = r1 >> 2, q = r1 & 3;
    int tid = threadIdx.x;

    {                                        // finalize this batch's 16 groups
        float2 pv = partials[b * 256 + tid];
        float s = pv.x, s2 = pv.y;
        #pragma unroll
        for (int d = 1; d < 16; d <<= 1) {
            s  += __shfl_xor(s, d);
            s2 += __shfl_xor(s2, d);
        }
        if ((tid & 15) == 0) {
            const float invN = 1.f / 36864.f;
            float mean = s * invN;
            float var  = s2 * invN - mean * mean;
            sgld[(tid >> 4) * 2]     = mean;
            sgld[(tid >> 4) * 2 + 1] = rsqrtf(var + 1e-5f);
        }
    }
    #pragma unroll
    for (int i = 0; i < 6; ++i) {            // stage raw 64c x 24x
        int idx = i * 256 + tid;             // 1536
        int c = idx / 24, xx = idx - c * 24;
        tin[c * 25 + xx] = x[((size_t)(b * CIN + c)) * HW + y * Ww + q * 24 + xx];
    }
    __syncthreads();
    #pragma unroll
    for (int i = 0; i < 6; ++i) {
        int idx = i * 256 + tid;
        int xx = idx >> 6, c = idx & 63;
        float v = tin[c * 25 + xx];
        float val = (v - sgld[(c >> 2) * 2]) * sgld[(c >> 2) * 2 + 1] * gw[c] + gb[c];
        unsigned short hi = f2bf(val);
        unsigned short lo = f2bf(val - bf2f(hi));
        size_t dst = ((size_t)(b * 98 + y + 1) * 98 + q * 24 + xx + 1) * 64 + c;
        xh[dst] = hi; xl[dst] = lo;
    }
}

#define MFMA3(ACC, AH, AL, BH, BL) \
    ACC = __builtin_amdgcn_mfma_f32_16x16x32_bf16(AL, BH, ACC, 0, 0, 0); \
    ACC = __builtin_amdgcn_mfma_f32_16x16x32_bf16(AH, BL, ACC, 0, 0, 0); \
    ACC = __builtin_amdgcn_mfma_f32_16x16x32_bf16(AH, BH, ACC, 0, 0, 0);

// --- fused MFMA (bf16x3): conv + GELU + QKV; 256 thr, 4 waves ---
// block = 4x8 pos x 128 oc; wave = ALL 32 pos x 32 oc (2x2 frags) -> B reuse x2
__global__ __launch_bounds__(256) void convqkv_kernel(
    const unsigned short* __restrict__ xh, const unsigned short* __restrict__ xl,
    const unsigned short* __restrict__ wch, const unsigned short* __restrict__ wcl,
    const float* __restrict__ cb,
    const unsigned short* __restrict__ wqh, const unsigned short* __restrict__ wql,
    const float* __restrict__ qbias, const float* __restrict__ kbias,
    const float* __restrict__ vbias,
    float* __restrict__ qo, float* __restrict__ ko, float* __restrict__ vo)
{
    __shared__ __align__(16) short ph_s[3840];   // [6r][10c][64ch] swizzled, hi
    __shared__ __align__(16) short pl_s[3840];   // lo
    __shared__ __align__(16) short fh_s[4096];   // [32 pos][128 c] swizzled, hi
    __shared__ __align__(16) short fl_s[4096];   // lo
    int bid = blockIdx.x;
    int swz = (bid & 7) * 72 + (bid >> 3);   // 576 = 8*72, bijective
    int b = swz / 288, rem = swz - b * 288;
    int ty = rem / 12, tx = rem - ty * 12;
    int y0 = ty * 4, x0 = tx * 8;
    int tid = threadIdx.x;

    for (int g = tid; g < 480; g += 256) {   // stage 6x10x64 patch hi/lo
        int row = g / 80, r2 = g - row * 80;
        int col = r2 >> 3, gc = r2 & 7;
        size_t srcoff = ((size_t)(b * 98 + y0 + row) * 98 + x0 + col) * 64 + gc * 8;
        int dst = ((row * 10 + col) << 6) + ((gc ^ (col & 7)) << 3);
        *(short8*)&ph_s[dst] = *(const short8*)(xh + srcoff);
        *(short8*)&pl_s[dst] = *(const short8*)(xl + srcoff);
    }
    __syncthreads();

    int ocg = tid >> 6, l = tid & 63;
    int l15 = l & 15, l4 = l >> 4;
    int oc0 = ocg * 32;
    int p0 = l15, p1 = 16 + l15;
    int r0 = p0 >> 3, xc = p0 & 7;           // p1: rows r0+2, same xc

    f32x4 c00 = {0.f,0.f,0.f,0.f}, c01 = {0.f,0.f,0.f,0.f};
    f32x4 c10 = {0.f,0.f,0.f,0.f}, c11 = {0.f,0.f,0.f,0.f};

    #pragma unroll 3
    for (int s = 0; s < 9; ++s) {
        int dy = s / 3, dx = s - dy * 3;
        int colA = xc + dx, cswz = (colA & 7) << 3;
        #pragma unroll
        for (int ch = 0; ch < 2; ++ch) {
            int gr = (ch * 4 + l4) << 3;
            int ai0 = (((r0 + dy) * 10 + colA) << 6) + (gr ^ cswz);
            int ai1 = (((r0 + 2 + dy) * 10 + colA) << 6) + (gr ^ cswz);
            short8 a0h = *(const short8*)&ph_s[ai0];
            short8 a0l = *(const short8*)&pl_s[ai0];
            short8 a1h = *(const short8*)&ph_s[ai1];
            short8 a1l = *(const short8*)&pl_s[ai1];
            int s2 = s * 2 + ch;
            int wb = ((s2 * 4 + ocg) * 2) * 512 + l * 8;
            short8 b0h = *(const short8*)(wch + wb);
            short8 b0l = *(const short8*)(wcl + wb);
            short8 b1h = *(const short8*)(wch + wb + 512);
            short8 b1l = *(const short8*)(wcl + wb + 512);
            MFMA3(c00, a0h, a0l, b0h, b0l)
            MFMA3(c01, a0h, a0l, b1h, b1l)
            MFMA3(c10, a1h, a1l, b0h, b0l)
            MFMA3(c11, a1h, a1l, b1h, b1l)
        }
    }

    // bias + exact GELU -> hi/lo bf16 -> swizzled f LDS
    float bias0 = cb[oc0 + l15], bias1 = cb[oc0 + 16 + l15];
    #pragma unroll
    for (int mf = 0; mf < 2; ++mf) {
        #pragma unroll
        for (int nf = 0; nf < 2; ++nf) {
            f32x4 a = (mf == 0) ? (nf == 0 ? c00 : c01) : (nf == 0 ? c10 : c11);
            float bs = nf == 0 ? bias0 : bias1;
            int oc = oc0 + nf * 16 + l15;
            #pragma unroll
            for (int rr = 0; rr < 4; ++rr) {
                int p = mf * 16 + l4 * 4 + rr;
                float v = a[rr] + bs;
                float g = 0.5f * v * (1.f + erff(v * 0.70710678118654752f));
                unsigned short hi = f2bf(g);
                unsigned short lo = f2bf(g - bf2f(hi));
                int di = p * 128 + ((((oc >> 3) ^ (p & 7)) << 3) | (oc & 7));
                fh_s[di] = (short)hi;
                fl_s[di] = (short)lo;
            }
        }
    }
    __syncthreads();

    // ---- QKV GEMM: A reloaded from LDS per m (caps VGPR), B = repacked wq ----
    int sw0 = (p0 & 7) << 3, sw1 = (p1 & 7) << 3;
    #pragma unroll 1
    for (int m = 0; m < 3; ++m) {
        const float* Bi = (m == 0) ? qbias : (m == 1) ? kbias : vbias;
        float* Om = (m == 0) ? qo : (m == 1) ? ko : vo;
        f32x4 d00 = {0.f,0.f,0.f,0.f}, d01 = {0.f,0.f,0.f,0.f};
        f32x4 d10 = {0.f,0.f,0.f,0.f}, d11 = {0.f,0.f,0.f,0.f};
        #pragma unroll
        for (int kc2 = 0; kc2 < 4; ++kc2) {
            int gr2 = (kc2 * 4 + l4) << 3;
            int i0 = p0 * 128 + (gr2 ^ sw0);
            int i1 = p1 * 128 + (gr2 ^ sw1);
            short8 ah0 = *(const short8*)&fh_s[i0];
            short8 al0 = *(const short8*)&fl_s[i0];
            short8 ah1 = *(const short8*)&fh_s[i1];
            short8 al1 = *(const short8*)&fl_s[i1];
            int wb = (((m * 4 + kc2) * 4 + ocg) * 2) * 512 + l * 8;
            short8 b0h = *(const short8*)(wqh + wb);
            short8 b0l = *(const short8*)(wql + wb);
            short8 b1h = *(const short8*)(wqh + wb + 512);
            short8 b1l = *(const short8*)(wql + wb + 512);
            MFMA3(d00, ah0, al0, b0h, b0l)
            MFMA3(d01, ah0, al0, b1h, b1l)
            MFMA3(d10, ah1, al1, b0h, b0l)
            MFMA3(d11, ah1, al1, b1h, b1l)
        }
        float bm0 = Bi[oc0 + l15], bm1 = Bi[oc0 + 16 + l15];
        #pragma unroll
        for (int mf = 0; mf < 2; ++mf) {
            #pragma unroll
            for (int nf = 0; nf < 2; ++nf) {
                f32x4 a = (mf == 0) ? (nf == 0 ? d00 : d01) : (nf == 0 ? d10 : d11);
                float bs = nf == 0 ? bm0 : bm1;
                int oc = oc0 + nf * 16 + l15;
                #pragma unroll
                for (int rr = 0; rr < 4; ++rr) {
                    int p = mf * 16 + l4 * 4 + rr;
                    int yy = y0 + (p >> 3), xx = x0 + (p & 7);
                    Om[((size_t)(b * HW + yy * Ww + xx)) * CMID + oc] = a[rr] + bs;
                }
            }
        }
    }
}

// ---- 7x7 NAT: block = 4x4 queries; K-union (10x10 rows) staged in LDS ----
__global__ __launch_bounds__(256) void nat_kernel(const float* __restrict__ q,
    const float* __restrict__ k, const float* __restrict__ v,
    float* __restrict__ out)
{
    __shared__ __align__(16) float Kl[12800];    // 100 rows x 128 ch, swizzled
    int bid = blockIdx.x;
    int swz = (bid & 7) * 144 + (bid >> 3);  // 1152 = 8*144, bijective
    int b = swz / 576, rem = swz - b * 576;
    int ti = rem / 24, tj = rem - ti * 24;
    int i0 = ti * 4, j0 = tj * 4;
    int ui = i0 - 3; ui = ui < 0 ? 0 : (ui > 86 ? 86 : ui);
    int uj = j0 - 3; uj = uj < 0 ? 0 : (uj > 86 ? 86 : uj);
    int tid = threadIdx.x;

    // stage K union: 100 rows x 32 float4, granule-XOR swizzle by (row&7)
    const float4* ksrc = (const float4*)k;
    float4* Kl4 = (float4*)Kl;
    #pragma unroll
    for (int it = 0; it < 13; ++it) {
        int idx = it * 256 + tid;
        if (idx < 3200) {
            int row = idx >> 5, c4 = idx & 31;
            int ur = row / 10, uc = row - ur * 10;
            size_t gp = ((size_t)(b * HW + (ui + ur) * Ww + (uj + uc))) * 32 + c4;
            Kl4[row * 32 + (c4 ^ (row & 7))] = ksrc[gp];
        }
    }
    __syncthreads();

    int wid = tid >> 6, lane = tid & 63;
    int gy = wid >> 1, gx = wid & 1;
    int iq0 = i0 + 2 * gy, jq0 = j0 + 2 * gx;

    int si0 = iq0 - 3; si0 = si0 < 0 ? 0 : (si0 > 89 ? 89 : si0);
    int si1 = iq0 - 2; si1 = si1 < 0 ? 0 : (si1 > 89 ? 89 : si1);
    int sj0 = jq0 - 3; sj0 = sj0 < 0 ? 0 : (sj0 > 89 ? 89 : sj0);
    int sj1 = jq0 - 2; sj1 = sj1 < 0 ? 0 : (sj1 > 89 ? 89 : sj1);
    int gsi = si0 > 88 ? 88 : si0;
    int gsj = sj0 > 88 ? 88 : sj0;
    int oi0 = si0 - gsi, oi1 = si1 - gsi, oj0 = sj0 - gsj, oj1 = sj1 - gsj;
    int goi = gsi - ui, goj = gsj - uj;      // 0..2 within the 10x10 union

    int wr = lane >> 3, wc = lane & 7;
    int R = (goi + wr) * 10 + (goj + wc);
    int Rs = R * 32, Rx = R & 7;

    // QK: lane's K row from LDS, dotted against the group's 4 queries (s_loads)
    const float4* qp0 = (const float4*)(q + (size_t)(b * HW + iq0 * Ww + jq0) * CMID);
    float a0 = 0.f, a1 = 0.f, a2 = 0.f, a3 = 0.f;
    #pragma unroll 8
    for (int c = 0; c < 32; ++c) {
        float4 kv = Kl4[Rs + (c ^ Rx)];
        float4 q0 = qp0[c], q1 = qp0[c + 32], q2 = qp0[c + 3072], q3 = qp0[c + 3104];
        a0 = fmaf(q0.x, kv.x, a0); a0 = fmaf(q0.y, kv.y, a0);
        a0 = fmaf(q0.z, kv.z, a0); a0 = fmaf(q0.w, kv.w, a0);
        a1 = fmaf(q1.x, kv.x, a1); a1 = fmaf(q1.y, kv.y, a1);
        a1 = fmaf(q1.z, kv.z, a1); a1 = fmaf(q1.w, kv.w, a1);
        a2 = fmaf(q2.x, kv.x, a2); a2 = fmaf(q2.y, kv.y, a2);
        a2 = fmaf(q2.z, kv.z, a2); a2 = fmaf(q2.w, kv.w, a2);
        a3 = fmaf(q3.x, kv.x, a3); a3 = fmaf(q3.y, kv.y, a3);
        a3 = fmaf(q3.z, kv.z, a3); a3 = fmaf(q3.w, kv.w, a3);
    }

    float l0 = ((unsigned)(wr - oi0) <= 6u && (unsigned)(wc - oj0) <= 6u) ? a0 * NAT_SCALE : -INFINITY;
    float l1 = ((unsigned)(wr - oi0) <= 6u && (unsigned)(wc - oj1) <= 6u) ? a1 * NAT_SCALE : -INFINITY;
    float l2 = ((unsigned)(wr - oi1) <= 6u && (unsigned)(wc - oj0) <= 6u) ? a2 * NAT_SCALE : -INFINITY;
    float l3 = ((unsigned)(wr - oi1) <= 6u && (unsigned)(wc - oj1) <= 6u) ? a3 * NAT_SCALE : -INFINITY;
    float m0 = l0, m1 = l1, m2 = l2, m3 = l3;
    #pragma unroll
    for (int d = 1; d < 64; d <<= 1) {
        m0 = fmaxf(m0, __shfl_xor(m0, d)); m1 = fmaxf(m1, __shfl_xor(m1, d));
        m2 = fmaxf(m2, __shfl_xor(m2, d)); m3 = fmaxf(m3, __shfl_xor(m3, d));
    }
    float e0 = __expf(l0 - m0), e1 = __expf(l1 - m1);
    float e2 = __expf(l2 - m2), e3 = __expf(l3 - m3);
    float s0 = e0, s1 = e1, s2 = e2, s3 = e3;
    #pragma unroll
    for (int d = 1; d < 64; d <<= 1) {
        s0 += __shfl_xor(s0, d); s1 += __shfl_xor(s1, d);
        s2 += __shfl_xor(s2, d); s3 += __shfl_xor(s3, d);
    }
    float w0 = e0 / s0, w1 = e1 / s1, w2 = e2 / s2, w3 = e3 / s3;

    // PV over the group's 8x8 window rows; V from global (coalesced, L2-hot)
    int base2 = b * HW + gsi * Ww + gsj;
    const float2* vbase = (const float2*)(v + (size_t)base2 * CMID);
    float2 o0 = {0.f, 0.f}, o1 = {0.f, 0.f}, o2 = {0.f, 0.f}, o3 = {0.f, 0.f};
    #pragma unroll
    for (int w = 0; w < 64; ++w) {
        int off = ((w >> 3) * Ww + (w & 7)) * 64;
        float2 vv = vbase[off + lane];
        float b0 = __shfl(w0, w), b1 = __shfl(w1, w);
        float b2 = __shfl(w2, w), b3 = __shfl(w3, w);
        o0.x = fmaf(b0, vv.x, o0.x); o0.y = fmaf(b0, vv.y, o0.y);
        o1.x = fmaf(b1, vv.x, o1.x); o1.y = fmaf(b1, vv.y, o1.y);
        o2.x = fmaf(b2, vv.x, o2.x); o2.y = fmaf(b2, vv.y, o2.y);
        o3.x = fmaf(b3, vv.x, o3.x); o3.y = fmaf(b3, vv.y, o3.y);
    }

    size_t ob = ((size_t)(b * CMID + 2 * lane)) * HW + iq0 * Ww + jq0;
    float2 r0 = {o0.x, o1.x}, r1 = {o0.y, o1.y};
    float2 r2 = {o2.x, o3.x}, r3 = {o2.y, o3.y};
    *(float2*)(out + ob)           = r0;
    *(float2*)(out + ob + HW)      = r1;
    *(float2*)(out + ob + Ww)      = r2;
    *(float2*)(out + ob + HW + Ww) = r3;
}

extern "C" void kernel_launch(void* const* d_in, const int* in_sizes, int n_in,
                              void* d_out, int out_size, void* d_ws, size_t ws_size,
                              hipStream_t stream) {
    const float* x      = (const float*)d_in[0];
    const float* gn_w   = (const float*)d_in[1];
    const float* gn_b   = (const float*)d_in[2];
    const float* conv_w = (const float*)d_in[3];
    const float* conv_b = (const float*)d_in[4];
    const float* q_w    = (const float*)d_in[5];
    const float* q_b    = (const float*)d_in[6];
    const float* k_w    = (const float*)d_in[7];
    const float* k_b    = (const float*)d_in[8];
    const float* v_w    = (const float*)d_in[9];
    const float* v_b    = (const float*)d_in[10];

    const size_t XNP = (size_t)2 * 98 * 98 * 64;      // 1,229,312 per plane
    float* ws    = (float*)d_ws;
    float2* partials = (float2*)ws;                    // 512 float2
    float* qb_   = ws + 1024;                          // 3 x 2,359,296 fp32 NHWC
    float* kb_   = qb_ + (size_t)2 * CMID * HW;
    float* vb_   = kb_ + (size_t)2 * CMID * HW;
    unsigned short* xnh = (unsigned short*)(vb_ + (size_t)2 * CMID * HW);
    unsigned short* xnl = xnh + XNP;
    unsigned short* wch = xnl + XNP;                   // 73,728 each
    unsigned short* wcl = wch + 73728;
    unsigned short* wqh = wcl + 73728;                 // 49,152 each
    unsigned short* wql = wqh + 49152;

    prep_kernel<<<1017, 256, 0, stream>>>(x, partials, conv_w, q_w, k_w, v_w,
                                          wch, wcl, wqh, wql, xnh, xnl);
    gnapply_kernel<<<768, 256, 0, stream>>>(x, partials, gn_w, gn_b, xnh, xnl);
    convqkv_kernel<<<576, 256, 0, stream>>>(xnh, xnl, wch, wcl, conv_b,
                                            wqh, wql, q_b, k_b, v_b,
                                            qb_, kb_, vb_);
    nat_kernel<<<1152, 256, 0, stream>>>(qb_, kb_, vb_, (float*)d_out);
}

// Round 13
// 74.972 us; speedup vs baseline: 8.6590x; 1.0112x over previous
//
#include <hip/hip_runtime.h>
#include <math.h>

#define Hh 96
#define Ww 96
#define HW 9216
#define CIN 64
#define CMID 128
#define NAT_SCALE 11.313708498984761f   // sqrt(128), multiplies logits

typedef __attribute__((ext_vector_type(4))) float f32x4;
typedef __attribute__((ext_vector_type(8))) short short8;

__device__ __forceinline__ unsigned short f2bf(float x) {
    union { float f; unsigned u; } v; v.f = x;
    unsigned r = v.u + 0x7FFF + ((v.u >> 16) & 1);     // RNE
    return (unsigned short)(r >> 16);
}
__device__ __forceinline__ float bf2f(unsigned short h) {
    union { unsigned u; float f; } v; v.u = (unsigned)h << 16;
    return v.f;
}

// ---- prep: gn partial sums (512 blk) + weight repack (480 blk) ----
__global__ __launch_bounds__(256) void prep_kernel(const float* __restrict__ x,
    float2* __restrict__ partials,
    const float* __restrict__ cw, const float* __restrict__ qw,
    const float* __restrict__ kw_, const float* __restrict__ vw,
    unsigned short* __restrict__ wch, unsigned short* __restrict__ wcl,
    unsigned short* __restrict__ wqh, unsigned short* __restrict__ wql)
{
    int bid = blockIdx.x, tid = threadIdx.x;
    if (bid < 512) {                         // GN partial sums
        size_t base = (size_t)(bid >> 4) * 36864 + (size_t)(bid & 15) * 2304;
        float s = 0.f, s2 = 0.f;
        #pragma unroll
        for (int i = 0; i < 9; ++i) {
            float v = x[base + i * 256 + tid];
            s += v; s2 += v * v;
        }
        #pragma unroll
        for (int d = 1; d < 64; d <<= 1) {
            s  += __shfl_xor(s, d);
            s2 += __shfl_xor(s2, d);
        }
        __shared__ float as[4], as2[4];
        int wid = tid >> 6, lane = tid & 63;
        if (lane == 0) { as[wid] = s; as2[wid] = s2; }
        __syncthreads();
        if (tid == 0) {
            float2 r = { as[0]+as[1]+as[2]+as[3], as2[0]+as2[1]+as2[2]+as2[3] };
            partials[bid] = r;
        }
    } else {                                 // weight repack
        int t = (bid - 512) * 256 + tid;     // < 122880
        if (t < 73728) {
            int e = t & 7, l = (t >> 3) & 63, fr = (t >> 9) & 1;
            int ocg = (t >> 10) & 3, s2 = t >> 12;      // 0..17
            int s = s2 >> 1, ch = s2 & 1;
            int oc = ocg * 32 + fr * 16 + (l & 15);
            int c  = ch * 32 + (l >> 4) * 8 + e;
            float v = cw[oc * 576 + c * 9 + s];
            unsigned short hi = f2bf(v);
            wch[t] = hi; wcl[t] = f2bf(v - bf2f(hi));
        } else {
            int t2 = t - 73728;              // < 49152
            int e = t2 & 7, l = (t2 >> 3) & 63, fr = (t2 >> 9) & 1;
            int ocg = (t2 >> 10) & 3, kc2 = (t2 >> 12) & 3, m = t2 >> 14;
            int oc = ocg * 32 + fr * 16 + (l & 15);
            int c  = kc2 * 32 + (l >> 4) * 8 + e;
            const float* W = (m == 0) ? qw : (m == 1) ? kw_ : vw;
            float v = W[oc * 128 + c];
            unsigned short hi = f2bf(v);
            wqh[t2] = hi; wql[t2] = f2bf(v - bf2f(hi));
        }
    }
}

#define MFMA3(ACC, AH, AL, BH, BL) \
    ACC = __builtin_amdgcn_mfma_f32_16x16x32_bf16(AL, BH, ACC, 0, 0, 0); \
    ACC = __builtin_amdgcn_mfma_f32_16x16x32_bf16(AH, BL, ACC, 0, 0, 0); \
    ACC = __builtin_amdgcn_mfma_f32_16x16x32_bf16(AH, BH, ACC, 0, 0, 0);

// --- fused MFMA (bf16x3): GN-apply + 3x3 conv + GELU + QKV; 256 thr ---
// block = 4x8 pos x 128 oc; wave = 32 pos x 32 oc (2x2 frags)
__global__ __launch_bounds__(256) void convqkv_kernel(
    const float* __restrict__ x, const float2* __restrict__ partials,
    const float* __restrict__ gw, const float* __restrict__ gb,
    const unsigned short* __restrict__ wch, const unsigned short* __restrict__ wcl,
    const float* __restrict__ cb,
    const unsigned short* __restrict__ wqh, const unsigned short* __restrict__ wql,
    const float* __restrict__ qbias, const float* __restrict__ kbias,
    const float* __restrict__ vbias,
    float* __restrict__ qo, float* __restrict__ ko, float* __restrict__ vo)
{
    __shared__ __align__(16) short ph_s[3840];   // [6r][10c][64ch] swizzled, hi
    __shared__ __align__(16) short pl_s[3840];   // lo
    __shared__ __align__(16) short fh_s[4096];   // [32 pos][128 c] swizzled, hi
    __shared__ __align__(16) short fl_s[4096];   // lo
    __shared__ float sgld[32];                   // 16 groups x {mean, rstd}
    int bid = blockIdx.x;
    int swz = (bid & 7) * 72 + (bid >> 3);   // 576 = 8*72, bijective
    int b = swz / 288, rem = swz - b * 288;
    int ty = rem / 12, tx = rem - ty * 12;
    int y0 = ty * 4, x0 = tx * 8;
    int tid = threadIdx.x;

    // issue raw-x loads for the 6x10x64 patch (position-fastest: 40B segments)
    float raw[15];
    #pragma unroll
    for (int it = 0; it < 15; ++it) {
        int idx = it * 256 + tid;            // 3840
        int c = idx / 60, p = idx - c * 60;
        int row = p / 10, col = p - row * 10;
        int gy = y0 - 1 + row, gx = x0 - 1 + col;
        float v = 0.f;
        if ((unsigned)gy < 96u && (unsigned)gx < 96u)
            v = x[((size_t)(b * CIN + c)) * HW + gy * Ww + gx];
        raw[it] = v;
    }

    {                                        // finalize this batch's 16 groups
        float2 pv = partials[b * 256 + tid];
        float s = pv.x, s2 = pv.y;
        #pragma unroll
        for (int d = 1; d < 16; d <<= 1) {
            s  += __shfl_xor(s, d);
            s2 += __shfl_xor(s2, d);
        }
        if ((tid & 15) == 0) {
            const float invN = 1.f / 36864.f;
            float mean = s * invN;
            float var  = s2 * invN - mean * mean;
            sgld[(tid >> 4) * 2]     = mean;
            sgld[(tid >> 4) * 2 + 1] = rsqrtf(var + 1e-5f);
        }
    }
    __syncthreads();

    #pragma unroll
    for (int it = 0; it < 15; ++it) {        // GN (in-bounds only) -> swizzled LDS
        int idx = it * 256 + tid;
        int c = idx / 60, p = idx - c * 60;
        int row = p / 10, col = p - row * 10;
        int gy = y0 - 1 + row, gx = x0 - 1 + col;
        bool ok = ((unsigned)gy < 96u && (unsigned)gx < 96u);
        float val = ok ? ((raw[it] - sgld[(c >> 2) * 2]) * sgld[(c >> 2) * 2 + 1]
                          * gw[c] + gb[c]) : 0.f;     // pad-with-0 is POST-GN
        unsigned short hi = f2bf(val);
        unsigned short lo = f2bf(val - bf2f(hi));
        int di = ((row * 10 + col) << 6) + ((((c >> 3) ^ (col & 7)) << 3) | (c & 7));
        ph_s[di] = (short)hi;
        pl_s[di] = (short)lo;
    }
    __syncthreads();

    int ocg = tid >> 6, l = tid & 63;
    int l15 = l & 15, l4 = l >> 4;
    int oc0 = ocg * 32;
    int p0 = l15, p1 = 16 + l15;
    int r0 = p0 >> 3, xc = p0 & 7;           // p1: rows r0+2, same xc

    f32x4 c00 = {0.f,0.f,0.f,0.f}, c01 = {0.f,0.f,0.f,0.f};
    f32x4 c10 = {0.f,0.f,0.f,0.f}, c11 = {0.f,0.f,0.f,0.f};

    #pragma unroll 3
    for (int s = 0; s < 9; ++s) {
        int dy = s / 3, dx = s - dy * 3;
        int colA = xc + dx, cswz = (colA & 7) << 3;
        #pragma unroll
        for (int ch = 0; ch < 2; ++ch) {
            int gr = (ch * 4 + l4) << 3;
            int ai0 = (((r0 + dy) * 10 + colA) << 6) + (gr ^ cswz);
            int ai1 = (((r0 + 2 + dy) * 10 + colA) << 6) + (gr ^ cswz);
            short8 a0h = *(const short8*)&ph_s[ai0];
            short8 a0l = *(const short8*)&pl_s[ai0];
            short8 a1h = *(const short8*)&ph_s[ai1];
            short8 a1l = *(const short8*)&pl_s[ai1];
            int s2 = s * 2 + ch;
            int wb = ((s2 * 4 + ocg) * 2) * 512 + l * 8;
            short8 b0h = *(const short8*)(wch + wb);
            short8 b0l = *(const short8*)(wcl + wb);
            short8 b1h = *(const short8*)(wch + wb + 512);
            short8 b1l = *(const short8*)(wcl + wb + 512);
            MFMA3(c00, a0h, a0l, b0h, b0l)
            MFMA3(c01, a0h, a0l, b1h, b1l)
            MFMA3(c10, a1h, a1l, b0h, b0l)
            MFMA3(c11, a1h, a1l, b1h, b1l)
        }
    }

    // bias + exact GELU -> hi/lo bf16 -> swizzled f LDS
    float bias0 = cb[oc0 + l15], bias1 = cb[oc0 + 16 + l15];
    #pragma unroll
    for (int mf = 0; mf < 2; ++mf) {
        #pragma unroll
        for (int nf = 0; nf < 2; ++nf) {
            f32x4 a = (mf == 0) ? (nf == 0 ? c00 : c01) : (nf == 0 ? c10 : c11);
            float bs = nf == 0 ? bias0 : bias1;
            int oc = oc0 + nf * 16 + l15;
            #pragma unroll
            for (int rr = 0; rr < 4; ++rr) {
                int p = mf * 16 + l4 * 4 + rr;
                float v = a[rr] + bs;
                float g = 0.5f * v * (1.f + erff(v * 0.70710678118654752f));
                unsigned short hi = f2bf(g);
                unsigned short lo = f2bf(g - bf2f(hi));
                int di = p * 128 + ((((oc >> 3) ^ (p & 7)) << 3) | (oc & 7));
                fh_s[di] = (short)hi;
                fl_s[di] = (short)lo;
            }
        }
    }
    __syncthreads();

    // ---- QKV GEMM: A reloaded from LDS per m (caps VGPR), B = repacked wq ----
    int sw0 = (p0 & 7) << 3, sw1 = (p1 & 7) << 3;
    #pragma unroll 1
    for (int m = 0; m < 3; ++m) {
        const float* Bi = (m == 0) ? qbias : (m == 1) ? kbias : vbias;
        float* Om = (m == 0) ? qo : (m == 1) ? ko : vo;
        f32x4 d00 = {0.f,0.f,0.f,0.f}, d01 = {0.f,0.f,0.f,0.f};
        f32x4 d10 = {0.f,0.f,0.f,0.f}, d11 = {0.f,0.f,0.f,0.f};
        #pragma unroll
        for (int kc2 = 0; kc2 < 4; ++kc2) {
            int gr2 = (kc2 * 4 + l4) << 3;
            int i0 = p0 * 128 + (gr2 ^ sw0);
            int i1 = p1 * 128 + (gr2 ^ sw1);
            short8 ah0 = *(const short8*)&fh_s[i0];
            short8 al0 = *(const short8*)&fl_s[i0];
            short8 ah1 = *(const short8*)&fh_s[i1];
            short8 al1 = *(const short8*)&fl_s[i1];
            int wb = (((m * 4 + kc2) * 4 + ocg) * 2) * 512 + l * 8;
            short8 b0h = *(const short8*)(wqh + wb);
            short8 b0l = *(const short8*)(wql + wb);
            short8 b1h = *(const short8*)(wqh + wb + 512);
            short8 b1l = *(const short8*)(wql + wb + 512);
            MFMA3(d00, ah0, al0, b0h, b0l)
            MFMA3(d01, ah0, al0, b1h, b1l)
            MFMA3(d10, ah1, al1, b0h, b0l)
            MFMA3(d11, ah1, al1, b1h, b1l)
        }
        float bm0 = Bi[oc0 + l15], bm1 = Bi[oc0 + 16 + l15];
        #pragma unroll
        for (int mf = 0; mf < 2; ++mf) {
            #pragma unroll
            for (int nf = 0; nf < 2; ++nf) {
                f32x4 a = (mf == 0) ? (nf == 0 ? d00 : d01) : (nf == 0 ? d10 : d11);
                float bs = nf == 0 ? bm0 : bm1;
                int oc = oc0 + nf * 16 + l15;
                #pragma unroll
                for (int rr = 0; rr < 4; ++rr) {
                    int p = mf * 16 + l4 * 4 + rr;
                    int yy = y0 + (p >> 3), xx = x0 + (p & 7);
                    Om[((size_t)(b * HW + yy * Ww + xx)) * CMID + oc] = a[rr] + bs;
                }
            }
        }
    }
}

// ---- 7x7 NAT: block = 4x4 queries; K-union (10x10 rows) staged in LDS ----
__global__ __launch_bounds__(256) void nat_kernel(const float* __restrict__ q,
    const float* __restrict__ k, const float* __restrict__ v,
    float* __restrict__ out)
{
    __shared__ __align__(16) float Kl[12800];    // 100 rows x 128 ch, swizzled
    int bid = blockIdx.x;
    int swz = (bid & 7) * 144 + (bid >> 3);  // 1152 = 8*144, bijective
    int b = swz / 576, rem = swz - b * 576;
    int ti = rem / 24, tj = rem - ti * 24;
    int i0 = ti * 4, j0 = tj * 4;
    int ui = i0 - 3; ui = ui < 0 ? 0 : (ui > 86 ? 86 : ui);
    int uj = j0 - 3; uj = uj < 0 ? 0 : (uj > 86 ? 86 : uj);
    int tid = threadIdx.x;

    // stage K union: 100 rows x 32 float4, granule-XOR swizzle by (row&7)
    const float4* ksrc = (const float4*)k;
    float4* Kl4 = (float4*)Kl;
    #pragma unroll
    for (int it = 0; it < 13; ++it) {
        int idx = it * 256 + tid;
        if (idx < 3200) {
            int row = idx >> 5, c4 = idx & 31;
            int ur = row / 10, uc = row - ur * 10;
            size_t gp = ((size_t)(b * HW + (ui + ur) * Ww + (uj + uc))) * 32 + c4;
            Kl4[row * 32 + (c4 ^ (row & 7))] = ksrc[gp];
        }
    }
    __syncthreads();

    int wid = tid >> 6, lane = tid & 63;
    int gy = wid >> 1, gx = wid & 1;
    int iq0 = i0 + 2 * gy, jq0 = j0 + 2 * gx;

    int si0 = iq0 - 3; si0 = si0 < 0 ? 0 : (si0 > 89 ? 89 : si0);
    int si1 = iq0 - 2; si1 = si1 < 0 ? 0 : (si1 > 89 ? 89 : si1);
    int sj0 = jq0 - 3; sj0 = sj0 < 0 ? 0 : (sj0 > 89 ? 89 : sj0);
    int sj1 = jq0 - 2; sj1 = sj1 < 0 ? 0 : (sj1 > 89 ? 89 : sj1);
    int gsi = si0 > 88 ? 88 : si0;
    int gsj = sj0 > 88 ? 88 : sj0;
    int oi0 = si0 - gsi, oi1 = si1 - gsi, oj0 = sj0 - gsj, oj1 = sj1 - gsj;
    int goi = gsi - ui, goj = gsj - uj;      // 0..2 within the 10x10 union

    int wr = lane >> 3, wc = lane & 7;
    int R = (goi + wr) * 10 + (goj + wc);
    int Rs = R * 32, Rx = R & 7;

    // QK: lane's K row from LDS, dotted against the group's 4 queries (s_loads)
    const float4* qp0 = (const float4*)(q + (size_t)(b * HW + iq0 * Ww + jq0) * CMID);
    float a0 = 0.f, a1 = 0.f, a2 = 0.f, a3 = 0.f;
    #pragma unroll 8
    for (int c = 0; c < 32; ++c) {
        float4 kv = Kl4[Rs + (c ^ Rx)];
        float4 q0 = qp0[c], q1 = qp0[c + 32], q2 = qp0[c + 3072], q3 = qp0[c + 3104];
        a0 = fmaf(q0.x, kv.x, a0); a0 = fmaf(q0.y, kv.y, a0);
        a0 = fmaf(q0.z, kv.z, a0); a0 = fmaf(q0.w, kv.w, a0);
        a1 = fmaf(q1.x, kv.x, a1); a1 = fmaf(q1.y, kv.y, a1);
        a1 = fmaf(q1.z, kv.z, a1); a1 = fmaf(q1.w, kv.w, a1);
        a2 = fmaf(q2.x, kv.x, a2); a2 = fmaf(q2.y, kv.y, a2);
        a2 = fmaf(q2.z, kv.z, a2); a2 = fmaf(q2.w, kv.w, a2);
        a3 = fmaf(q3.x, kv.x, a3); a3 = fmaf(q3.y, kv.y, a3);
        a3 = fmaf(q3.z, kv.z, a3); a3 = fmaf(q3.w, kv.w, a3);
    }

    float l0 = ((unsigned)(wr - oi0) <= 6u && (unsigned)(wc - oj0) <= 6u) ? a0 * NAT_SCALE : -INFINITY;
    float l1 = ((unsigned)(wr - oi0) <= 6u && (unsigned)(wc - oj1) <= 6u) ? a1 * NAT_SCALE : -INFINITY;
    float l2 = ((unsigned)(wr - oi1) <= 6u && (unsigned)(wc - oj0) <= 6u) ? a2 * NAT_SCALE : -INFINITY;
    float l3 = ((unsigned)(wr - oi1) <= 6u && (unsigned)(wc - oj1) <= 6u) ? a3 * NAT_SCALE : -INFINITY;
    float m0 = l0, m1 = l1, m2 = l2, m3 = l3;
    #pragma unroll
    for (int d = 1; d < 64; d <<= 1) {
        m0 = fmaxf(m0, __shfl_xor(m0, d)); m1 = fmaxf(m1, __shfl_xor(m1, d));
        m2 = fmaxf(m2, __shfl_xor(m2, d)); m3 = fmaxf(m3, __shfl_xor(m3, d));
    }
    float e0 = __expf(l0 - m0), e1 = __expf(l1 - m1);
    float e2 = __expf(l2 - m2), e3 = __expf(l3 - m3);
    float s0 = e0, s1 = e1, s2 = e2, s3 = e3;
    #pragma unroll
    for (int d = 1; d < 64; d <<= 1) {
        s0 += __shfl_xor(s0, d); s1 += __shfl_xor(s1, d);
        s2 += __shfl_xor(s2, d); s3 += __shfl_xor(s3, d);
    }
    float w0 = e0 / s0, w1 = e1 / s1, w2 = e2 / s2, w3 = e3 / s3;

    // PV over the group's 8x8 window rows; V from global (coalesced, L2-hot)
    int base2 = b * HW + gsi * Ww + gsj;
    const float2* vbase = (const float2*)(v + (size_t)base2 * CMID);
    float2 o0 = {0.f, 0.f}, o1 = {0.f, 0.f}, o2 = {0.f, 0.f}, o3 = {0.f, 0.f};
    #pragma unroll
    for (int w = 0; w < 64; ++w) {
        int off = ((w >> 3) * Ww + (w & 7)) * 64;
        float2 vv = vbase[off + lane];
        float b0 = __shfl(w0, w), b1 = __shfl(w1, w);
        float b2 = __shfl(w2, w), b3 = __shfl(w3, w);
        o0.x = fmaf(b0, vv.x, o0.x); o0.y = fmaf(b0, vv.y, o0.y);
        o1.x = fmaf(b1, vv.x, o1.x); o1.y = fmaf(b1, vv.y, o1.y);
        o2.x = fmaf(b2, vv.x, o2.x); o2.y = fmaf(b2, vv.y, o2.y);
        o3.x = fmaf(b3, vv.x, o3.x); o3.y = fmaf(b3, vv.y, o3.y);
    }

    size_t ob = ((size_t)(b * CMID + 2 * lane)) * HW + iq0 * Ww + jq0;
    float2 r0 = {o0.x, o1.x}, r1 = {o0.y, o1.y};
    float2 r2 = {o2.x, o3.x}, r3 = {o2.y, o3.y};
    *(float2*)(out + ob)           = r0;
    *(float2*)(out + ob + HW)      = r1;
    *(float2*)(out + ob + Ww)      = r2;
    *(float2*)(out + ob + HW + Ww) = r3;
}

extern "C" void kernel_launch(void* const* d_in, const int* in_sizes, int n_in,
                              void* d_out, int out_size, void* d_ws, size_t ws_size,
                              hipStream_t stream) {
    const float* x      = (const float*)d_in[0];
    const float* gn_w   = (const float*)d_in[1];
    const float* gn_b   = (const float*)d_in[2];
    const float* conv_w = (const float*)d_in[3];
    const float* conv_b = (const float*)d_in[4];
    const float* q_w    = (const float*)d_in[5];
    const float* q_b    = (const float*)d_in[6];
    const float* k_w    = (const float*)d_in[7];
    const float* k_b    = (const float*)d_in[8];
    const float* v_w    = (const float*)d_in[9];
    const float* v_b    = (const float*)d_in[10];

    float* ws    = (float*)d_ws;
    float2* partials = (float2*)ws;                    // 512 float2
    float* qb_   = ws + 1024;                          // 3 x 2,359,296 fp32 NHWC
    float* kb_   = qb_ + (size_t)2 * CMID * HW;
    float* vb_   = kb_ + (size_t)2 * CMID * HW;
    unsigned short* wch = (unsigned short*)(vb_ + (size_t)2 * CMID * HW);
    unsigned short* wcl = wch + 73728;                 // 73,728 each
    unsigned short* wqh = wcl + 73728;                 // 49,152 each
    unsigned short* wql = wqh + 49152;

    prep_kernel<<<992, 256, 0, stream>>>(x, partials, conv_w, q_w, k_w, v_w,
                                         wch, wcl, wqh, wql);
    convqkv_kernel<<<576, 256, 0, stream>>>(x, partials, gn_w, gn_b,
                                            wch, wcl, conv_b,
                                            wqh, wql, q_b, k_b, v_b,
                                            qb_, kb_, vb_);
    nat_kernel<<<1152, 256, 0, stream>>>(qb_, kb_, vb_, (float*)d_out);
}